// Round 5
// baseline (96.353 us; speedup 1.0000x reference)
//
#include <hip/hip_runtime.h>
#include <hip/hip_bf16.h>

#define BB 8
#define SS 256
#define CHAR_E 128
#define BI_E 64
#define EMBED 256
#define HH 256
#define NTAGS 17
#define SPAD 260   // S + 2 zero-pad rows each side
#define NROWS 2048 // B*S
#define NLOG2E -1.4426950408889634f

typedef __attribute__((ext_vector_type(8))) short short8;
typedef __attribute__((ext_vector_type(4))) float f32x4;
#define MFMA16(a, b, c) __builtin_amdgcn_mfma_f32_16x16x32_bf16(a, b, c, 0, 0, 0)

__device__ __forceinline__ float fast_rcp(float x) {
    return __builtin_amdgcn_rcpf(x);
}
__device__ __forceinline__ float fast_exp2(float x) {
    return __builtin_amdgcn_exp2f(x);
}
__device__ __forceinline__ float fast_tanh(float x) {
    float e = __expf(2.0f * x);
    return 1.0f - 2.0f * fast_rcp(e + 1.0f);
}

// ---- fused: embed gather -> xbf; pack WcombT, W01T; lengths -> Linv_buf ----
// WcombT col n = (h>>4)*48 + scale*16 + (h&15); rows kk = tap*256 + e.
__global__ __launch_bounds__(256) void embed_pack_kernel(
        const int* __restrict__ tokens,
        const float* __restrict__ char_emb,
        const float* __restrict__ bigram_emb,
        const float* __restrict__ w1, const float* __restrict__ w3,
        const float* __restrict__ w5,
        const float* __restrict__ W0, const float* __restrict__ W1mat,
        const int* __restrict__ masks,
        __hip_bfloat16* __restrict__ xbf,
        __hip_bfloat16* __restrict__ WcombT,
        __hip_bfloat16* __restrict__ W01T,
        float* __restrict__ Linv_buf) {
    int blk = blockIdx.x;
    int t = threadIdx.x;
    if (blk < BB * SPAD) {
        int b = blk / SPAD, r = blk % SPAD;
        float v = 0.0f;
        if (r >= 2 && r < SS + 2) {
            int s = r - 2;
            const int* tk = tokens + (b * SS + s) * 3;
            if (t < CHAR_E)              v = char_emb[tk[0] * CHAR_E + t];
            else if (t < CHAR_E + BI_E)  v = bigram_emb[tk[1] * BI_E + (t - CHAR_E)];
            else                         v = bigram_emb[tk[2] * BI_E + (t - CHAR_E - BI_E)];
        }
        xbf[blk * EMBED + t] = __float2bfloat16(v);
    } else if (blk < BB * SPAD + 768) {
        int n = blk - BB * SPAD;
        int hc = n / 48, w16 = n % 48;
        int scale = w16 >> 4, hl = w16 & 15;
        int h = hc * 16 + hl;
        for (int kk = t; kk < 1280; kk += 256) {
            int tap = kk >> 8, e = kk & 255;
            float v = 0.f;
            if (scale == 0)      v = w5[(tap * EMBED + e) * HH + h];
            else if (scale == 1) { if (tap >= 1 && tap <= 3) v = w3[((tap - 1) * EMBED + e) * HH + h]; }
            else                 { if (tap == 2) v = w1[e * HH + h]; }
            WcombT[n * 1280 + kk] = __float2bfloat16(v);
        }
    } else if (blk < BB * SPAD + 768 + 512) {
        int n = blk - BB * SPAD - 768;   // 0..511
        float v = (n < 256) ? W0[t * HH + n] : W1mat[t * HH + (n - 256)];
        W01T[n * 256 + t] = __float2bfloat16(v);
    } else {
        if (t < BB) {
            int s = 0;
            for (int j = 0; j < SS; ++j) s += masks[t * SS + j];
            Linv_buf[t] = (s > 0) ? (1.0f / (float)s) : 0.0f;
        }
    }
}

// ---- conv as MFMA GEMM (M=2048,K=1280,N=768), epilogue tanh+max ------------
// writes cbf[row][h] (bf16, A for g-GEMM) and cmT[h][row] = c*m_j*Linv (f32).
__global__ __launch_bounds__(256) void conv_mfma_fused(
        const __hip_bfloat16* __restrict__ xbf,
        const __hip_bfloat16* __restrict__ WcombT,
        const float* __restrict__ cb1, const float* __restrict__ cb3,
        const float* __restrict__ cb5,
        const int* __restrict__ masks, const float* __restrict__ Linv_buf,
        __hip_bfloat16* __restrict__ cbf, float* __restrict__ cmT) {
    int blk = blockIdx.x;            // 64 m-tiles * 8 h-groups = 512
    int mt = blk >> 3, hg = blk & 7;
    int tid = threadIdx.x, w = tid >> 6, lane = tid & 63;
    int wm = w >> 1, wh = w & 1;
    int fr = lane & 15, fq = lane >> 4;
    int row0 = mt * 32 + wm * 16;
    int hc = hg * 2 + wh;            // h-chunk 0..15

    int i = row0 + fr;
    int b = i >> 8, s = i & 255;
    const short8* ap = (const short8*)(xbf + (b * SPAD + s) * EMBED + fq * 8);
    const short8* bp0 = (const short8*)(WcombT + (hc * 48 + 0 * 16 + fr) * 1280 + fq * 8);
    const short8* bp1 = (const short8*)(WcombT + (hc * 48 + 1 * 16 + fr) * 1280 + fq * 8);
    const short8* bp2 = (const short8*)(WcombT + (hc * 48 + 2 * 16 + fr) * 1280 + fq * 8);

    f32x4 acc[3] = {};
    #pragma unroll 4
    for (int ks = 0; ks < 40; ++ks) {
        short8 a = ap[ks * 4];
        acc[0] = MFMA16(a, bp0[ks * 4], acc[0]);
        acc[1] = MFMA16(a, bp1[ks * 4], acc[1]);
        acc[2] = MFMA16(a, bp2[ks * 4], acc[2]);
    }

    int h = hc * 16 + fr;
    float bb5 = cb5[h], bb3 = cb3[h], bb1 = cb1[h];
    float Linv = Linv_buf[row0 >> 8];    // 16-row tile never crosses b
    #pragma unroll
    for (int j = 0; j < 4; ++j) {
        int row = row0 + fq * 4 + j;
        float t5 = fast_tanh(acc[0][j] + bb5);
        float t3 = fast_tanh(acc[1][j] + bb3);
        float t1 = fast_tanh(acc[2][j] + bb1);
        float v = fmaxf(t1, fmaxf(t3, t5));
        cbf[row * HH + h] = __float2bfloat16(v);
        cmT[h * NROWS + row] = v * (float)masks[row] * Linv;
    }
}

// ---- g0/g1 GEMM (M=2048,K=256,N=512); writes E = exp2(-log2e*(v+bias)) ----
// TRANSPOSED: E0T/E1T [h][row], so relation reads are coalesced/uniform.
__global__ __launch_bounds__(256) void gemm_g_mfma_kernel(
        const __hip_bfloat16* __restrict__ cbf,
        const __hip_bfloat16* __restrict__ W01T,
        const float* __restrict__ b0, const float* __restrict__ b1v,
        float* __restrict__ E0T, float* __restrict__ E1T) {
    int blk = blockIdx.x;            // 64 m-tiles * 8 n-tiles = 512
    int by = blk >> 3, bx = blk & 7;
    int tid = threadIdx.x;
    int w = tid >> 6, lane = tid & 63;
    int wr = w >> 1, wc = w & 1;
    int m0 = by * 32 + wr * 16;
    int n0 = bx * 64 + wc * 32;
    int fr = lane & 15, fq = lane >> 4;

    const short8* ap = (const short8*)(cbf + (m0 + fr) * HH + fq * 8);
    const short8* bptr[2];
    #pragma unroll
    for (int n = 0; n < 2; ++n)
        bptr[n] = (const short8*)(W01T + (n0 + n * 16 + fr) * HH + fq * 8);

    f32x4 acc[2] = {};
    #pragma unroll
    for (int ks = 0; ks < 8; ++ks) {
        short8 a = ap[ks * 4];
        acc[0] = MFMA16(a, bptr[0][ks * 4], acc[0]);
        acc[1] = MFMA16(a, bptr[1][ks * 4], acc[1]);
    }
    #pragma unroll
    for (int n = 0; n < 2; ++n) {
        int col = n0 + n * 16 + fr;
        float bias = (col < 256) ? b0[col] : b1v[col - 256];
        float* dst = (col < 256) ? (E0T + col * NROWS)
                                 : (E1T + (col - 256) * NROWS);
        #pragma unroll
        for (int j = 0; j < 4; ++j) {
            int row = m0 + fq * 4 + j;
            dst[row] = fast_exp2(NLOG2E * (acc[n][j] + bias));
        }
    }
}

// ---- relation: block=(b, h-quad); threads=i; FULL j-sum in one pass --------
// acc[c] = sum_j rcp(1 + E0T[h][i]*E1T[h][j]) * cmT[h][j]; per-j loads uniform.
__global__ __launch_bounds__(256) void relation_kernel(
        const float* __restrict__ E0T, const float* __restrict__ E1T,
        const float* __restrict__ cmT, const int* __restrict__ masks,
        float* __restrict__ rel) {
    int blk = blockIdx.x;            // b*64 + hq
    int b = blk >> 6, hq = blk & 63;
    int i = threadIdx.x;
    int row = b * SS + i;
    int h0 = hq * 4;

    float e0[4], acc[4];
    #pragma unroll
    for (int c = 0; c < 4; ++c) {
        e0[c] = E0T[(h0 + c) * NROWS + row];
        acc[c] = 0.f;
    }

    const float* e1base = E1T + b * SS;
    const float* cmbase = cmT + b * SS;
    #pragma unroll 4
    for (int j = 0; j < SS; ++j) {
        #pragma unroll
        for (int c = 0; c < 4; ++c) {
            float e1 = e1base[(h0 + c) * NROWS + j];   // block-uniform -> s_load
            float cm = cmbase[(h0 + c) * NROWS + j];   // block-uniform -> s_load
            float sg = fast_rcp(fmaf(e0[c], e1, 1.0f));
            acc[c] = fmaf(sg, cm, acc[c]);
        }
    }

    float mi = (float)masks[row];
    #pragma unroll
    for (int c = 0; c < 4; ++c)
        rel[row * HH + h0 + c] = fast_tanh(acc[c] * mi);
}

// ---- final: rel @ Wo + bo -> softmax -> out --------------------------------
__global__ __launch_bounds__(256) void final_kernel(
        const float* __restrict__ rel,
        const float* __restrict__ Wo, const float* __restrict__ bo,
        float* __restrict__ out) {
    int blk = blockIdx.x;            // b*64 + iblk
    int b = blk >> 6;
    int i0 = (blk & 63) * 4;
    int tid = threadIdx.x;

    __shared__ float lg[4][NTAGS];

    int grp = tid >> 6, lane = tid & 63;
    int i = i0 + grp;
    if (lane < NTAGS) {
        const float* rrow = rel + (b * SS + i) * HH;   // wave-uniform row
        float lacc = bo[lane];
        #pragma unroll 8
        for (int hh = 0; hh < HH; ++hh)
            lacc = fmaf(rrow[hh], Wo[hh * NTAGS + lane], lacc);
        lg[grp][lane] = lacc;
    }
    __syncthreads();

    if (tid < 4) {
        float mx = -1e30f;
        #pragma unroll
        for (int t = 0; t < NTAGS; ++t) mx = fmaxf(mx, lg[tid][t]);
        float ex[NTAGS], sum = 0.f;
        #pragma unroll
        for (int t = 0; t < NTAGS; ++t) { ex[t] = __expf(lg[tid][t] - mx); sum += ex[t]; }
        float si = fast_rcp(sum);
        int ii = i0 + tid;
        #pragma unroll
        for (int t = 0; t < NTAGS; ++t)
            out[(b * SS + ii) * NTAGS + t] = ex[t] * si;
    }
}

extern "C" void kernel_launch(void* const* d_in, const int* in_sizes, int n_in,
                              void* d_out, int out_size, void* d_ws, size_t ws_size,
                              hipStream_t stream) {
    const int*   tokens     = (const int*)d_in[0];
    const int*   masks      = (const int*)d_in[1];
    const float* char_emb   = (const float*)d_in[2];
    const float* bigram_emb = (const float*)d_in[3];
    const float* conv1_w    = (const float*)d_in[4];
    const float* conv1_b    = (const float*)d_in[5];
    const float* conv3_w    = (const float*)d_in[6];
    const float* conv3_b    = (const float*)d_in[7];
    const float* conv5_w    = (const float*)d_in[8];
    const float* conv5_b    = (const float*)d_in[9];
    const float* W0         = (const float*)d_in[10];
    const float* b0         = (const float*)d_in[11];
    const float* W1         = (const float*)d_in[12];
    const float* b1         = (const float*)d_in[13];
    const float* Wo         = (const float*)d_in[14];
    const float* bo         = (const float*)d_in[15];
    float* out = (float*)d_out;

    char* p = (char*)d_ws;
    __hip_bfloat16* xbf    = (__hip_bfloat16*)p;  p += BB * SPAD * EMBED * 2;   // 1.06 MB
    __hip_bfloat16* WcombT = (__hip_bfloat16*)p;  p += 768 * 1280 * 2;          // 1.97 MB
    __hip_bfloat16* W01T   = (__hip_bfloat16*)p;  p += 512 * 256 * 2;           // 0.26 MB
    __hip_bfloat16* cbf    = (__hip_bfloat16*)p;  p += NROWS * HH * 2;          // 1.05 MB
    float* cmT  = (float*)p;  p += HH * NROWS * 4;                              // 2.1 MB
    float* E0T  = (float*)p;  p += HH * NROWS * 4;                              // 2.1 MB
    float* E1T  = (float*)p;  p += HH * NROWS * 4;                              // 2.1 MB
    float* rel  = (float*)p;  p += NROWS * HH * 4;                              // 2.1 MB
    float* Linv_buf = (float*)p;  p += 64;

    embed_pack_kernel<<<BB * SPAD + 768 + 512 + 1, 256, 0, stream>>>(
        tokens, char_emb, bigram_emb, conv1_w, conv3_w, conv5_w, W0, W1,
        masks, xbf, WcombT, W01T, Linv_buf);
    conv_mfma_fused<<<512, 256, 0, stream>>>(xbf, WcombT, conv1_b, conv3_b,
                                             conv5_b, masks, Linv_buf, cbf, cmT);
    gemm_g_mfma_kernel<<<512, 256, 0, stream>>>(cbf, W01T, b0, b1, E0T, E1T);
    relation_kernel<<<BB * 64, 256, 0, stream>>>(E0T, E1T, cmT, masks, rel);
    final_kernel<<<BB * 64, 256, 0, stream>>>(rel, Wo, bo, out);
}

// Round 6
// 95.678 us; speedup vs baseline: 1.0071x; 1.0071x over previous
//
#include <hip/hip_runtime.h>
#include <hip/hip_bf16.h>

#define BB 8
#define SS 256
#define CHAR_E 128
#define BI_E 64
#define EMBED 256
#define HH 256
#define NTAGS 17
#define SPAD 260   // S + 2 zero-pad rows each side
#define NROWS 2048 // B*S
#define NLOG2E -1.4426950408889634f

typedef __attribute__((ext_vector_type(8))) short short8;
typedef __attribute__((ext_vector_type(4))) float f32x4;
#define MFMA16(a, b, c) __builtin_amdgcn_mfma_f32_16x16x32_bf16(a, b, c, 0, 0, 0)

__device__ __forceinline__ float fast_rcp(float x) {
    return __builtin_amdgcn_rcpf(x);
}
__device__ __forceinline__ float fast_exp2(float x) {
    return __builtin_amdgcn_exp2f(x);
}
__device__ __forceinline__ float fast_tanh(float x) {
    float e = __expf(2.0f * x);
    return 1.0f - 2.0f * fast_rcp(e + 1.0f);
}

// ---- fused: embed gather -> xbf; pack WcombT, W01T; lengths -> Linv_buf ----
// WcombT col n = (h>>4)*48 + scale*16 + (h&15); rows kk = tap*256 + e.
__global__ __launch_bounds__(256) void embed_pack_kernel(
        const int* __restrict__ tokens,
        const float* __restrict__ char_emb,
        const float* __restrict__ bigram_emb,
        const float* __restrict__ w1, const float* __restrict__ w3,
        const float* __restrict__ w5,
        const float* __restrict__ W0, const float* __restrict__ W1mat,
        const int* __restrict__ masks,
        __hip_bfloat16* __restrict__ xbf,
        __hip_bfloat16* __restrict__ WcombT,
        __hip_bfloat16* __restrict__ W01T,
        float* __restrict__ Linv_buf) {
    int blk = blockIdx.x;
    int t = threadIdx.x;
    if (blk < BB * SPAD) {
        int b = blk / SPAD, r = blk % SPAD;
        float v = 0.0f;
        if (r >= 2 && r < SS + 2) {
            int s = r - 2;
            const int* tk = tokens + (b * SS + s) * 3;
            if (t < CHAR_E)              v = char_emb[tk[0] * CHAR_E + t];
            else if (t < CHAR_E + BI_E)  v = bigram_emb[tk[1] * BI_E + (t - CHAR_E)];
            else                         v = bigram_emb[tk[2] * BI_E + (t - CHAR_E - BI_E)];
        }
        xbf[blk * EMBED + t] = __float2bfloat16(v);
    } else if (blk < BB * SPAD + 768) {
        int n = blk - BB * SPAD;
        int hc = n / 48, w16 = n % 48;
        int scale = w16 >> 4, hl = w16 & 15;
        int h = hc * 16 + hl;
        for (int kk = t; kk < 1280; kk += 256) {
            int tap = kk >> 8, e = kk & 255;
            float v = 0.f;
            if (scale == 0)      v = w5[(tap * EMBED + e) * HH + h];
            else if (scale == 1) { if (tap >= 1 && tap <= 3) v = w3[((tap - 1) * EMBED + e) * HH + h]; }
            else                 { if (tap == 2) v = w1[e * HH + h]; }
            WcombT[n * 1280 + kk] = __float2bfloat16(v);
        }
    } else if (blk < BB * SPAD + 768 + 512) {
        int n = blk - BB * SPAD - 768;   // 0..511
        float v = (n < 256) ? W0[t * HH + n] : W1mat[t * HH + (n - 256)];
        W01T[n * 256 + t] = __float2bfloat16(v);
    } else {
        // lengths: b = t>>5, 32 lanes each sum 8 masks, shuffle-reduce
        int b = t >> 5, l = t & 31;
        int ssum = 0;
        #pragma unroll
        for (int k = 0; k < 8; ++k) ssum += masks[b * SS + l * 8 + k];
        #pragma unroll
        for (int o = 16; o; o >>= 1) ssum += __shfl_xor(ssum, o);
        if (l == 0) Linv_buf[b] = (ssum > 0) ? (1.0f / (float)ssum) : 0.0f;
    }
}

// ---- conv as MFMA GEMM (M=2048,K=1280,N=768), epilogue tanh+max ------------
// writes cbf[row][h] (bf16) and cm[row][h] = c*m*Linv (f32, row-major).
__global__ __launch_bounds__(256, 2) void conv_mfma_fused(
        const __hip_bfloat16* __restrict__ xbf,
        const __hip_bfloat16* __restrict__ WcombT,
        const float* __restrict__ cb1, const float* __restrict__ cb3,
        const float* __restrict__ cb5,
        const int* __restrict__ masks, const float* __restrict__ Linv_buf,
        __hip_bfloat16* __restrict__ cbf, float* __restrict__ cm) {
    int blk = blockIdx.x;            // 64 m-tiles * 8 h-groups = 512
    int mt = blk >> 3, hg = blk & 7;
    int tid = threadIdx.x, w = tid >> 6, lane = tid & 63;
    int wm = w >> 1, wh = w & 1;
    int fr = lane & 15, fq = lane >> 4;
    int row0 = mt * 32 + wm * 16;
    int hc = hg * 2 + wh;            // h-chunk 0..15

    int i = row0 + fr;
    int b = i >> 8, s = i & 255;
    const short8* ap = (const short8*)(xbf + (b * SPAD + s) * EMBED + fq * 8);
    const short8* bp0 = (const short8*)(WcombT + (hc * 48 + 0 * 16 + fr) * 1280 + fq * 8);
    const short8* bp1 = (const short8*)(WcombT + (hc * 48 + 1 * 16 + fr) * 1280 + fq * 8);
    const short8* bp2 = (const short8*)(WcombT + (hc * 48 + 2 * 16 + fr) * 1280 + fq * 8);

    f32x4 acc0 = {}, acc1 = {}, acc2 = {};
    #pragma unroll 8
    for (int ks = 0; ks < 40; ++ks) {
        short8 a  = ap[ks * 4];
        short8 f0 = bp0[ks * 4];
        short8 f1 = bp1[ks * 4];
        short8 f2 = bp2[ks * 4];
        acc0 = MFMA16(a, f0, acc0);
        acc1 = MFMA16(a, f1, acc1);
        acc2 = MFMA16(a, f2, acc2);
    }

    int h = hc * 16 + fr;
    float bb5 = cb5[h], bb3 = cb3[h], bb1 = cb1[h];
    float Linv = Linv_buf[row0 >> 8];    // 16-row tile never crosses b
    #pragma unroll
    for (int j = 0; j < 4; ++j) {
        int row = row0 + fq * 4 + j;
        float t5 = fast_tanh(acc0[j] + bb5);
        float t3 = fast_tanh(acc1[j] + bb3);
        float t1 = fast_tanh(acc2[j] + bb1);
        float v = fmaxf(t1, fmaxf(t3, t5));
        cbf[row * HH + h] = __float2bfloat16(v);
        cm[row * HH + h] = v * (float)masks[row] * Linv;
    }
}

// ---- g0/g1 GEMM (M=2048,K=256,N=512); writes E = exp2(-log2e*(v+bias)) ----
// E0T transposed [h][row] (relation's per-thread reads coalesce);
// E1 row-major [row][h] (relation stages per-j slices into LDS).
__global__ __launch_bounds__(256, 2) void gemm_g_mfma_kernel(
        const __hip_bfloat16* __restrict__ cbf,
        const __hip_bfloat16* __restrict__ W01T,
        const float* __restrict__ b0, const float* __restrict__ b1v,
        float* __restrict__ E0T, float* __restrict__ E1) {
    int blk = blockIdx.x;            // 64 m-tiles * 8 n-tiles = 512
    int by = blk >> 3, bx = blk & 7;
    int tid = threadIdx.x;
    int w = tid >> 6, lane = tid & 63;
    int wr = w >> 1, wc = w & 1;
    int m0 = by * 32 + wr * 16;
    int n0 = bx * 64 + wc * 32;
    int fr = lane & 15, fq = lane >> 4;

    const short8* ap = (const short8*)(cbf + (m0 + fr) * HH + fq * 8);
    const short8* bptr0 = (const short8*)(W01T + (n0 + fr) * HH + fq * 8);
    const short8* bptr1 = (const short8*)(W01T + (n0 + 16 + fr) * HH + fq * 8);

    f32x4 acc[2] = {};
    #pragma unroll
    for (int ks = 0; ks < 8; ++ks) {
        short8 a = ap[ks * 4];
        acc[0] = MFMA16(a, bptr0[ks * 4], acc[0]);
        acc[1] = MFMA16(a, bptr1[ks * 4], acc[1]);
    }
    #pragma unroll
    for (int n = 0; n < 2; ++n) {
        int col = n0 + n * 16 + fr;
        float bias = (col < 256) ? b0[col] : b1v[col - 256];
        #pragma unroll
        for (int j = 0; j < 4; ++j) {
            int row = m0 + fq * 4 + j;
            float ev = fast_exp2(NLOG2E * (acc[n][j] + bias));
            if (col < 256) E0T[col * NROWS + row] = ev;
            else           E1[row * HH + (col - 256)] = ev;
        }
    }
}

// ---- relation: block=(b, h-pair); threads=i; LDS-staged j-slices -----------
// acc[c] = sum_j rcp(1 + E0T[h][i]*E1[j][h]) * cm[j][h]; per-j LDS broadcast.
__global__ __launch_bounds__(256) void relation_kernel(
        const float* __restrict__ E0T, const float* __restrict__ E1,
        const float* __restrict__ cm, const int* __restrict__ masks,
        float* __restrict__ rel) {
    int blk = blockIdx.x;            // b*128 + hp
    int b = blk >> 7, hp = blk & 127;
    int i = threadIdx.x;
    int row = b * SS + i;
    int h0 = hp * 2;

    __shared__ float e1s[2][SS];
    __shared__ float cms[2][SS];
    {
        const float* e1p = E1 + row * HH + h0;
        const float* cmp = cm + row * HH + h0;
        e1s[0][i] = e1p[0]; e1s[1][i] = e1p[1];
        cms[0][i] = cmp[0]; cms[1][i] = cmp[1];
    }
    __syncthreads();

    float e0a = E0T[(h0    ) * NROWS + row];
    float e0b = E0T[(h0 + 1) * NROWS + row];
    float acca = 0.f, accb = 0.f;
    #pragma unroll 8
    for (int j = 0; j < SS; ++j) {
        float sga = fast_rcp(fmaf(e0a, e1s[0][j], 1.0f));
        float sgb = fast_rcp(fmaf(e0b, e1s[1][j], 1.0f));
        acca = fmaf(sga, cms[0][j], acca);
        accb = fmaf(sgb, cms[1][j], accb);
    }
    float mi = (float)masks[row];
    rel[row * HH + h0]     = fast_tanh(acca * mi);
    rel[row * HH + h0 + 1] = fast_tanh(accb * mi);
}

// ---- final: rel @ Wo + bo -> softmax -> out --------------------------------
__global__ __launch_bounds__(256) void final_kernel(
        const float* __restrict__ rel,
        const float* __restrict__ Wo, const float* __restrict__ bo,
        float* __restrict__ out) {
    int blk = blockIdx.x;            // b*64 + iblk
    int b = blk >> 6;
    int i0 = (blk & 63) * 4;
    int tid = threadIdx.x;

    __shared__ float lg[4][NTAGS];

    int grp = tid >> 6, lane = tid & 63;
    int i = i0 + grp;
    if (lane < NTAGS) {
        const float* rrow = rel + (b * SS + i) * HH;   // wave-uniform row
        float lacc = bo[lane];
        #pragma unroll 8
        for (int hh = 0; hh < HH; ++hh)
            lacc = fmaf(rrow[hh], Wo[hh * NTAGS + lane], lacc);
        lg[grp][lane] = lacc;
    }
    __syncthreads();

    if (tid < 4) {
        float mx = -1e30f;
        #pragma unroll
        for (int t = 0; t < NTAGS; ++t) mx = fmaxf(mx, lg[tid][t]);
        float ex[NTAGS], sum = 0.f;
        #pragma unroll
        for (int t = 0; t < NTAGS; ++t) { ex[t] = __expf(lg[tid][t] - mx); sum += ex[t]; }
        float si = fast_rcp(sum);
        int ii = i0 + tid;
        #pragma unroll
        for (int t = 0; t < NTAGS; ++t)
            out[(b * SS + ii) * NTAGS + t] = ex[t] * si;
    }
}

extern "C" void kernel_launch(void* const* d_in, const int* in_sizes, int n_in,
                              void* d_out, int out_size, void* d_ws, size_t ws_size,
                              hipStream_t stream) {
    const int*   tokens     = (const int*)d_in[0];
    const int*   masks      = (const int*)d_in[1];
    const float* char_emb   = (const float*)d_in[2];
    const float* bigram_emb = (const float*)d_in[3];
    const float* conv1_w    = (const float*)d_in[4];
    const float* conv1_b    = (const float*)d_in[5];
    const float* conv3_w    = (const float*)d_in[6];
    const float* conv3_b    = (const float*)d_in[7];
    const float* conv5_w    = (const float*)d_in[8];
    const float* conv5_b    = (const float*)d_in[9];
    const float* W0         = (const float*)d_in[10];
    const float* b0         = (const float*)d_in[11];
    const float* W1         = (const float*)d_in[12];
    const float* b1         = (const float*)d_in[13];
    const float* Wo         = (const float*)d_in[14];
    const float* bo         = (const float*)d_in[15];
    float* out = (float*)d_out;

    char* p = (char*)d_ws;
    __hip_bfloat16* xbf    = (__hip_bfloat16*)p;  p += BB * SPAD * EMBED * 2;   // 1.06 MB
    __hip_bfloat16* WcombT = (__hip_bfloat16*)p;  p += 768 * 1280 * 2;          // 1.97 MB
    __hip_bfloat16* W01T   = (__hip_bfloat16*)p;  p += 512 * 256 * 2;           // 0.26 MB
    __hip_bfloat16* cbf    = (__hip_bfloat16*)p;  p += NROWS * HH * 2;          // 1.05 MB
    float* cm   = (float*)p;  p += (size_t)NROWS * HH * 4;                      // 2.1 MB
    float* E0T  = (float*)p;  p += (size_t)HH * NROWS * 4;                      // 2.1 MB
    float* E1   = (float*)p;  p += (size_t)NROWS * HH * 4;                      // 2.1 MB
    float* rel  = (float*)p;  p += (size_t)NROWS * HH * 4;                      // 2.1 MB
    float* Linv_buf = (float*)p;  p += 64;

    embed_pack_kernel<<<BB * SPAD + 768 + 512 + 1, 256, 0, stream>>>(
        tokens, char_emb, bigram_emb, conv1_w, conv3_w, conv5_w, W0, W1,
        masks, xbf, WcombT, W01T, Linv_buf);
    conv_mfma_fused<<<512, 256, 0, stream>>>(xbf, WcombT, conv1_b, conv3_b,
                                             conv5_b, masks, Linv_buf, cbf, cm);
    gemm_g_mfma_kernel<<<512, 256, 0, stream>>>(cbf, W01T, b0, b1, E0T, E1);
    relation_kernel<<<BB * 128, 256, 0, stream>>>(E0T, E1, cm, masks, rel);
    final_kernel<<<BB * 64, 256, 0, stream>>>(rel, Wo, bo, out);
}

// Round 7
// 86.418 us; speedup vs baseline: 1.1150x; 1.1071x over previous
//
#include <hip/hip_runtime.h>
#include <hip/hip_bf16.h>

#define BB 8
#define SS 256
#define CHAR_E 128
#define BI_E 64
#define EMBED 256
#define HH 256
#define NTAGS 17
#define SPAD 260   // S + 2 zero-pad rows each side
#define NROWS 2048 // B*S
#define NLOG2E -1.4426950408889634f

typedef __attribute__((ext_vector_type(8))) short short8;
typedef __attribute__((ext_vector_type(4))) float f32x4;
typedef __attribute__((ext_vector_type(2))) float f32x2;
#define MFMA16(a, b, c) __builtin_amdgcn_mfma_f32_16x16x32_bf16(a, b, c, 0, 0, 0)

__device__ __forceinline__ float fast_rcp(float x) {
    return __builtin_amdgcn_rcpf(x);
}
__device__ __forceinline__ float fast_exp2(float x) {
    return __builtin_amdgcn_exp2f(x);
}
__device__ __forceinline__ float fast_tanh(float x) {
    float e = __expf(2.0f * x);
    return 1.0f - 2.0f * fast_rcp(e + 1.0f);
}

// ---- fused: embed gather -> xbf; pack WcombT/W01T (coalesced); lengths -----
// WcombT row n = (h>>4)*48 + scale*16 + (h&15); cols kk = tap*256 + e.
__global__ __launch_bounds__(256) void embed_pack_kernel(
        const int* __restrict__ tokens,
        const float* __restrict__ char_emb,
        const float* __restrict__ bigram_emb,
        const float* __restrict__ w1, const float* __restrict__ w3,
        const float* __restrict__ w5,
        const float* __restrict__ W0, const float* __restrict__ W1mat,
        const int* __restrict__ masks,
        __hip_bfloat16* __restrict__ xbf,
        __hip_bfloat16* __restrict__ WcombT,
        __hip_bfloat16* __restrict__ W01T,
        float* __restrict__ Linv_buf) {
    int blk = blockIdx.x;
    int t = threadIdx.x;
    if (blk < BB * SPAD) {
        int b = blk / SPAD, r = blk % SPAD;
        float v = 0.0f;
        if (r >= 2 && r < SS + 2) {
            int s = r - 2;
            const int* tk = tokens + (b * SS + s) * 3;
            if (t < CHAR_E)              v = char_emb[tk[0] * CHAR_E + t];
            else if (t < CHAR_E + BI_E)  v = bigram_emb[tk[1] * BI_E + (t - CHAR_E)];
            else                         v = bigram_emb[tk[2] * BI_E + (t - CHAR_E - BI_E)];
        }
        xbf[blk * EMBED + t] = __float2bfloat16(v);
    } else if (blk < BB * SPAD + 1280) {
        // WcombT pack: block = kk, threads = h (reads coalesced over h)
        int kk = blk - BB * SPAD;        // 0..1279
        int tap = kk >> 8, e = kk & 255;
        int h = t, hc = h >> 4, hl = h & 15;
        float v5 = w5[(tap * EMBED + e) * HH + h];
        float v3 = (tap >= 1 && tap <= 3) ? w3[((tap - 1) * EMBED + e) * HH + h] : 0.f;
        float v1 = (tap == 2) ? w1[e * HH + h] : 0.f;
        WcombT[(hc * 48 +  0 + hl) * 1280 + kk] = __float2bfloat16(v5);
        WcombT[(hc * 48 + 16 + hl) * 1280 + kk] = __float2bfloat16(v3);
        WcombT[(hc * 48 + 32 + hl) * 1280 + kk] = __float2bfloat16(v1);
    } else if (blk < BB * SPAD + 1280 + 256) {
        // W01T pack: block = e, threads = h (reads coalesced over h)
        int e = blk - BB * SPAD - 1280;
        W01T[t * 256 + e]         = __float2bfloat16(W0[e * HH + t]);
        W01T[(256 + t) * 256 + e] = __float2bfloat16(W1mat[e * HH + t]);
    } else {
        // lengths: b = t>>5, 32 lanes each sum 8 masks, shuffle-reduce
        int b = t >> 5, l = t & 31;
        int ssum = 0;
        #pragma unroll
        for (int k = 0; k < 8; ++k) ssum += masks[b * SS + l * 8 + k];
        #pragma unroll
        for (int o = 16; o; o >>= 1) ssum += __shfl_xor(ssum, o);
        if (l == 0) Linv_buf[b] = (ssum > 0) ? (1.0f / (float)ssum) : 0.0f;
    }
}

// ---- conv as LDS-tiled MFMA GEMM (BM=64, BN=48=3 scales x 16h, BK=64) ------
// T14 async-stage (load-early / ds_write-late), T2 XOR swizzle chunk^(row&7).
// Epilogue: tanh + max over scales -> cbf (bf16) + cm = c*m*Linv (f32).
__global__ __launch_bounds__(256, 2) void conv_mfma_fused(
        const __hip_bfloat16* __restrict__ xbf,
        const __hip_bfloat16* __restrict__ WcombT,
        const float* __restrict__ cb1, const float* __restrict__ cb3,
        const float* __restrict__ cb5,
        const int* __restrict__ masks, const float* __restrict__ Linv_buf,
        __hip_bfloat16* __restrict__ cbf, float* __restrict__ cm) {
    __shared__ short8 sA[2][512];    // [64 rows][8 chunks of 16B], swizzled
    __shared__ short8 sB[2][384];    // [48 rows][8 chunks]

    int blk = blockIdx.x;            // mt*16 + hc
    int mt = blk >> 4, hc = blk & 15;
    int tid = threadIdx.x, w = tid >> 6, lane = tid & 63;
    int fr = lane & 15, fq = lane >> 4;
    int row0 = mt * 64;
    int b = row0 >> 8, s0 = row0 & 255;
    const __hip_bfloat16* xbase = xbf + (b * SPAD + s0) * EMBED;
    const __hip_bfloat16* wbase = WcombT + (hc * 48) * 1280;

    short8 va[2], vb0, vb1;
    auto LOADG = [&](int q) {
        int tap = q >> 2, e0 = (q & 3) * 64;
        const __hip_bfloat16* xsrc = xbase + tap * EMBED + e0;
        const __hip_bfloat16* wsrc = wbase + q * 64;
        #pragma unroll
        for (int it = 0; it < 2; ++it) {
            int s = tid + it * 256, r = s >> 3, cg = s & 7;
            va[it] = *(const short8*)(xsrc + r * EMBED + cg * 8);
        }
        { int r = tid >> 3, cg = tid & 7;
          vb0 = *(const short8*)(wsrc + r * 1280 + cg * 8); }
        if (tid < 128) {
            int s = 256 + tid, r = s >> 3, cg = s & 7;
            vb1 = *(const short8*)(wsrc + r * 1280 + cg * 8);
        }
    };
    auto WRITE = [&](int buf) {
        #pragma unroll
        for (int it = 0; it < 2; ++it) {
            int s = tid + it * 256, r = s >> 3, cg = s & 7;
            sA[buf][r * 8 + (cg ^ (r & 7))] = va[it];
        }
        { int r = tid >> 3, cg = tid & 7;
          sB[buf][r * 8 + (cg ^ (r & 7))] = vb0; }
        if (tid < 128) {
            int s = 256 + tid, r = s >> 3, cg = s & 7;
            sB[buf][r * 8 + (cg ^ (r & 7))] = vb1;
        }
    };

    LOADG(0);
    WRITE(0);
    __syncthreads();

    f32x4 acc0 = {}, acc1 = {}, acc2 = {};
    int ra = w * 16 + fr;            // wave w owns rows w*16..w*16+15
    int cur = 0;
    for (int q = 0; q < 20; ++q) {
        if (q < 19) LOADG(q + 1);
        #pragma unroll
        for (int ksub = 0; ksub < 2; ++ksub) {
            int c = ksub * 4 + fq;
            short8 a  = sA[cur][ra * 8 + (c ^ (ra & 7))];
            short8 q0 = sB[cur][(fr     ) * 8 + (c ^ (fr & 7))];
            short8 q1 = sB[cur][(16 + fr) * 8 + (c ^ (fr & 7))];
            short8 q2 = sB[cur][(32 + fr) * 8 + (c ^ (fr & 7))];
            acc0 = MFMA16(a, q0, acc0);
            acc1 = MFMA16(a, q1, acc1);
            acc2 = MFMA16(a, q2, acc2);
        }
        if (q < 19) WRITE(cur ^ 1);
        __syncthreads();
        cur ^= 1;
    }

    int h = hc * 16 + fr;
    float bb5 = cb5[h], bb3 = cb3[h], bb1 = cb1[h];
    float Linv = Linv_buf[b];
    #pragma unroll
    for (int j = 0; j < 4; ++j) {
        int row = row0 + w * 16 + fq * 4 + j;
        float t5 = fast_tanh(acc0[j] + bb5);
        float t3 = fast_tanh(acc1[j] + bb3);
        float t1 = fast_tanh(acc2[j] + bb1);
        float v = fmaxf(t1, fmaxf(t3, t5));
        cbf[row * HH + h] = __float2bfloat16(v);
        cm[row * HH + h] = v * (float)masks[row] * Linv;
    }
}

// ---- g0/g1 GEMM (M=2048,K=256,N=512); writes E = exp2(-log2e*(v+bias)) ----
// E0/E1 row-major [row][h]; sigmoid(g0+g1) = rcp(1 + E0[i,h]*E1[j,h]).
__global__ __launch_bounds__(256, 2) void gemm_g_mfma_kernel(
        const __hip_bfloat16* __restrict__ cbf,
        const __hip_bfloat16* __restrict__ W01T,
        const float* __restrict__ b0, const float* __restrict__ b1v,
        float* __restrict__ E0, float* __restrict__ E1) {
    int blk = blockIdx.x;            // 64 m-tiles * 8 n-tiles = 512
    int by = blk >> 3, bx = blk & 7;
    int tid = threadIdx.x;
    int w = tid >> 6, lane = tid & 63;
    int wr = w >> 1, wc = w & 1;
    int m0 = by * 32 + wr * 16;
    int n0 = bx * 64 + wc * 32;
    int fr = lane & 15, fq = lane >> 4;

    const short8* ap = (const short8*)(cbf + (m0 + fr) * HH + fq * 8);
    const short8* bptr0 = (const short8*)(W01T + (n0 + fr) * HH + fq * 8);
    const short8* bptr1 = (const short8*)(W01T + (n0 + 16 + fr) * HH + fq * 8);

    f32x4 acc[2] = {};
    #pragma unroll
    for (int ks = 0; ks < 8; ++ks) {
        short8 a = ap[ks * 4];
        acc[0] = MFMA16(a, bptr0[ks * 4], acc[0]);
        acc[1] = MFMA16(a, bptr1[ks * 4], acc[1]);
    }
    #pragma unroll
    for (int n = 0; n < 2; ++n) {
        int col = n0 + n * 16 + fr;
        float bias = (col < 256) ? b0[col] : b1v[col - 256];
        float* dst = (col < 256) ? (E0 + col) : (E1 + col - 256);
        #pragma unroll
        for (int j = 0; j < 4; ++j) {
            int row = m0 + fq * 4 + j;
            dst[row * HH] = fast_exp2(NLOG2E * (acc[n][j] + bias));
        }
    }
}

// ---- relation: block=(b, h-pair); threads=i; one b128 LDS read per j -------
__global__ __launch_bounds__(256) void relation_kernel(
        const float* __restrict__ E0, const float* __restrict__ E1,
        const float* __restrict__ cm, const int* __restrict__ masks,
        float* __restrict__ rel) {
    int blk = blockIdx.x;            // b*128 + hp
    int b = blk >> 7, hp = blk & 127;
    int i = threadIdx.x;
    int row = b * SS + i;
    int h0 = hp * 2;

    __shared__ f32x4 pr[SS];         // {e1_h0, cm_h0, e1_h1, cm_h1} per j
    {
        f32x2 e1v = *(const f32x2*)(E1 + row * HH + h0);
        f32x2 cmv = *(const f32x2*)(cm + row * HH + h0);
        f32x4 pv;
        pv[0] = e1v[0]; pv[1] = cmv[0]; pv[2] = e1v[1]; pv[3] = cmv[1];
        pr[i] = pv;
    }
    __syncthreads();

    f32x2 e0v = *(const f32x2*)(E0 + row * HH + h0);
    float acca = 0.f, accb = 0.f;
    #pragma unroll 8
    for (int j = 0; j < SS; ++j) {
        f32x4 v = pr[j];
        acca = fmaf(fast_rcp(fmaf(e0v[0], v[0], 1.0f)), v[1], acca);
        accb = fmaf(fast_rcp(fmaf(e0v[1], v[2], 1.0f)), v[3], accb);
    }
    float mi = (float)masks[row];
    rel[row * HH + h0]     = fast_tanh(acca * mi);
    rel[row * HH + h0 + 1] = fast_tanh(accb * mi);
}

// ---- final: rel @ Wo + bo -> softmax -> out --------------------------------
__global__ __launch_bounds__(256) void final_kernel(
        const float* __restrict__ rel,
        const float* __restrict__ Wo, const float* __restrict__ bo,
        float* __restrict__ out) {
    int blk = blockIdx.x;            // b*64 + iblk
    int b = blk >> 6;
    int i0 = (blk & 63) * 4;
    int tid = threadIdx.x;

    __shared__ float lg[4][NTAGS];

    int grp = tid >> 6, lane = tid & 63;
    int i = i0 + grp;
    int p = lane / 17, tg = lane % 17;
    float lacc = 0.f;
    if (p < 3) {
        const float* rrow = rel + (b * SS + i) * HH;
        int hb = p * 85, he = (p == 2) ? 256 : (p * 85 + 85);
        for (int hh = hb; hh < he; ++hh)
            lacc = fmaf(rrow[hh], Wo[hh * NTAGS + tg], lacc);
    }
    float v1 = __shfl(lacc, tg + 17, 64);
    float v2 = __shfl(lacc, tg + 34, 64);
    if (lane < NTAGS) lg[grp][lane] = lacc + v1 + v2 + bo[lane];
    __syncthreads();

    if (tid < 4) {
        float mx = -1e30f;
        #pragma unroll
        for (int t = 0; t < NTAGS; ++t) mx = fmaxf(mx, lg[tid][t]);
        float ex[NTAGS], sum = 0.f;
        #pragma unroll
        for (int t = 0; t < NTAGS; ++t) { ex[t] = __expf(lg[tid][t] - mx); sum += ex[t]; }
        float si = fast_rcp(sum);
        int ii = i0 + tid;
        #pragma unroll
        for (int t = 0; t < NTAGS; ++t)
            out[(b * SS + ii) * NTAGS + t] = ex[t] * si;
    }
}

extern "C" void kernel_launch(void* const* d_in, const int* in_sizes, int n_in,
                              void* d_out, int out_size, void* d_ws, size_t ws_size,
                              hipStream_t stream) {
    const int*   tokens     = (const int*)d_in[0];
    const int*   masks      = (const int*)d_in[1];
    const float* char_emb   = (const float*)d_in[2];
    const float* bigram_emb = (const float*)d_in[3];
    const float* conv1_w    = (const float*)d_in[4];
    const float* conv1_b    = (const float*)d_in[5];
    const float* conv3_w    = (const float*)d_in[6];
    const float* conv3_b    = (const float*)d_in[7];
    const float* conv5_w    = (const float*)d_in[8];
    const float* conv5_b    = (const float*)d_in[9];
    const float* W0         = (const float*)d_in[10];
    const float* b0         = (const float*)d_in[11];
    const float* W1         = (const float*)d_in[12];
    const float* b1         = (const float*)d_in[13];
    const float* Wo         = (const float*)d_in[14];
    const float* bo         = (const float*)d_in[15];
    float* out = (float*)d_out;

    char* p = (char*)d_ws;
    __hip_bfloat16* xbf    = (__hip_bfloat16*)p;  p += BB * SPAD * EMBED * 2;   // 1.06 MB
    __hip_bfloat16* WcombT = (__hip_bfloat16*)p;  p += 768 * 1280 * 2;          // 1.97 MB
    __hip_bfloat16* W01T   = (__hip_bfloat16*)p;  p += 512 * 256 * 2;           // 0.26 MB
    __hip_bfloat16* cbf    = (__hip_bfloat16*)p;  p += NROWS * HH * 2;          // 1.05 MB
    float* cm  = (float*)p;  p += (size_t)NROWS * HH * 4;                       // 2.1 MB
    float* E0  = (float*)p;  p += (size_t)NROWS * HH * 4;                       // 2.1 MB
    float* E1  = (float*)p;  p += (size_t)NROWS * HH * 4;                       // 2.1 MB
    float* rel = (float*)p;  p += (size_t)NROWS * HH * 4;                       // 2.1 MB
    float* Linv_buf = (float*)p;  p += 64;

    embed_pack_kernel<<<BB * SPAD + 1280 + 256 + 1, 256, 0, stream>>>(
        tokens, char_emb, bigram_emb, conv1_w, conv3_w, conv5_w, W0, W1,
        masks, xbf, WcombT, W01T, Linv_buf);
    conv_mfma_fused<<<512, 256, 0, stream>>>(xbf, WcombT, conv1_b, conv3_b,
                                             conv5_b, masks, Linv_buf, cbf, cm);
    gemm_g_mfma_kernel<<<512, 256, 0, stream>>>(cbf, W01T, b0, b1, E0, E1);
    relation_kernel<<<BB * 128, 256, 0, stream>>>(E0, E1, cm, masks, rel);
    final_kernel<<<BB * 64, 256, 0, stream>>>(rel, Wo, bo, out);
}

// Round 8
// 79.419 us; speedup vs baseline: 1.2132x; 1.0881x over previous
//
#include <hip/hip_runtime.h>
#include <hip/hip_bf16.h>

#define BB 8
#define SS 256
#define CHAR_E 128
#define BI_E 64
#define EMBED 256
#define HH 256
#define NTAGS 17
#define SPAD 260   // S + 2 zero-pad rows each side
#define NROWS 2048 // B*S
#define NLOG2E -1.4426950408889634f

typedef __attribute__((ext_vector_type(8))) short short8;
typedef __attribute__((ext_vector_type(4))) float f32x4;
#define MFMA16(a, b, c) __builtin_amdgcn_mfma_f32_16x16x32_bf16(a, b, c, 0, 0, 0)

__device__ __forceinline__ float fast_rcp(float x) {
    return __builtin_amdgcn_rcpf(x);
}
__device__ __forceinline__ float fast_exp2(float x) {
    return __builtin_amdgcn_exp2f(x);
}
__device__ __forceinline__ float fast_tanh(float x) {
    float e = __expf(2.0f * x);
    return 1.0f - 2.0f * fast_rcp(e + 1.0f);
}

// ---- fused: embed gather -> xbf; pack WcombT/W01T; lengths -----------------
// WcombT row n = (h>>4)*48 + scale*16 + (h&15); cols kk = tap*256 + e.
__global__ __launch_bounds__(256) void embed_pack_kernel(
        const int* __restrict__ tokens,
        const float* __restrict__ char_emb,
        const float* __restrict__ bigram_emb,
        const float* __restrict__ w1, const float* __restrict__ w3,
        const float* __restrict__ w5,
        const float* __restrict__ W0, const float* __restrict__ W1mat,
        const int* __restrict__ masks,
        __hip_bfloat16* __restrict__ xbf,
        __hip_bfloat16* __restrict__ WcombT,
        __hip_bfloat16* __restrict__ W01T,
        float* __restrict__ Linv_buf) {
    int blk = blockIdx.x;
    int t = threadIdx.x;
    if (blk < BB * SPAD) {
        int b = blk / SPAD, r = blk % SPAD;
        float v = 0.0f;
        if (r >= 2 && r < SS + 2) {
            int s = r - 2;
            const int* tk = tokens + (b * SS + s) * 3;
            if (t < CHAR_E)              v = char_emb[tk[0] * CHAR_E + t];
            else if (t < CHAR_E + BI_E)  v = bigram_emb[tk[1] * BI_E + (t - CHAR_E)];
            else                         v = bigram_emb[tk[2] * BI_E + (t - CHAR_E - BI_E)];
        }
        xbf[blk * EMBED + t] = __float2bfloat16(v);
    } else if (blk < BB * SPAD + 160) {
        // WcombT pack: block = 8 kk-cols, thread = h; short8 (16B) stores
        int kk0 = (blk - BB * SPAD) * 8;
        int h = t, hc = h >> 4, hl = h & 15;
        union { short8 v; __hip_bfloat16 b[8]; } u5, u3, u1;
        #pragma unroll
        for (int k = 0; k < 8; ++k) {
            int kk = kk0 + k, tap = kk >> 8, e = kk & 255;
            float f5 = w5[(tap * EMBED + e) * HH + h];
            float f3 = (tap >= 1 && tap <= 3) ? w3[((tap - 1) * EMBED + e) * HH + h] : 0.f;
            float f1 = (tap == 2) ? w1[e * HH + h] : 0.f;
            u5.b[k] = __float2bfloat16(f5);
            u3.b[k] = __float2bfloat16(f3);
            u1.b[k] = __float2bfloat16(f1);
        }
        *(short8*)(WcombT + (hc * 48 +  0 + hl) * 1280 + kk0) = u5.v;
        *(short8*)(WcombT + (hc * 48 + 16 + hl) * 1280 + kk0) = u3.v;
        *(short8*)(WcombT + (hc * 48 + 32 + hl) * 1280 + kk0) = u1.v;
    } else if (blk < BB * SPAD + 160 + 256) {
        // W01T pack: block = e, threads = h (reads coalesced over h)
        int e = blk - BB * SPAD - 160;
        W01T[t * 256 + e]         = __float2bfloat16(W0[e * HH + t]);
        W01T[(256 + t) * 256 + e] = __float2bfloat16(W1mat[e * HH + t]);
    } else {
        // lengths: b = t>>5, 32 lanes each sum 8 masks, shuffle-reduce
        int b = t >> 5, l = t & 31;
        int ssum = 0;
        #pragma unroll
        for (int k = 0; k < 8; ++k) ssum += masks[b * SS + l * 8 + k];
        #pragma unroll
        for (int o = 16; o; o >>= 1) ssum += __shfl_xor(ssum, o);
        if (l == 0) Linv_buf[b] = (ssum > 0) ? (1.0f / (float)ssum) : 0.0f;
    }
}

// ---- conv as LDS-tiled MFMA GEMM (BM=64, BN=48, BK=128, dbuf) --------------
// 10 K-steps, 12 MFMA/step/wave; T2 swizzle chunk^(row&15); T14 load-early.
__global__ __launch_bounds__(256, 2) void conv_mfma_fused(
        const __hip_bfloat16* __restrict__ xbf,
        const __hip_bfloat16* __restrict__ WcombT,
        const float* __restrict__ cb1, const float* __restrict__ cb3,
        const float* __restrict__ cb5,
        const int* __restrict__ masks, const float* __restrict__ Linv_buf,
        __hip_bfloat16* __restrict__ cbf, float* __restrict__ cm) {
    __shared__ short8 sA[2][1024];   // [64 rows][16 chunks], 16KB per buf
    __shared__ short8 sB[2][768];    // [48 rows][16 chunks], 12KB per buf

    int blk = blockIdx.x;            // mt*16 + hc
    int mt = blk >> 4, hc = blk & 15;
    int tid = threadIdx.x, w = tid >> 6, lane = tid & 63;
    int fr = lane & 15, fq = lane >> 4;
    int row0 = mt * 64;
    int b = row0 >> 8, s0 = row0 & 255;
    const __hip_bfloat16* xbase = xbf + (b * SPAD + s0) * EMBED;
    const __hip_bfloat16* wbase = WcombT + (hc * 48) * 1280;

    short8 va[4], vb[3];
    auto LOADG = [&](int q) {
        int tap = q >> 1, e0 = (q & 1) * 128;
        const __hip_bfloat16* xs = xbase + tap * EMBED + e0;
        #pragma unroll
        for (int it = 0; it < 4; ++it) {
            int s = tid + it * 256, r = s >> 4, cg = s & 15;
            va[it] = *(const short8*)(xs + r * EMBED + cg * 8);
        }
        const __hip_bfloat16* wsrc = wbase + q * 128;
        #pragma unroll
        for (int it = 0; it < 3; ++it) {
            int s = tid + it * 256, r = s >> 4, cg = s & 15;
            vb[it] = *(const short8*)(wsrc + r * 1280 + cg * 8);
        }
    };
    auto WRITE = [&](int buf) {
        #pragma unroll
        for (int it = 0; it < 4; ++it) {
            int s = tid + it * 256, r = s >> 4, cg = s & 15;
            sA[buf][r * 16 + (cg ^ (r & 15))] = va[it];
        }
        #pragma unroll
        for (int it = 0; it < 3; ++it) {
            int s = tid + it * 256, r = s >> 4, cg = s & 15;
            sB[buf][r * 16 + (cg ^ (r & 15))] = vb[it];
        }
    };

    LOADG(0);
    WRITE(0);
    __syncthreads();

    f32x4 acc0 = {}, acc1 = {}, acc2 = {};
    int ra = w * 16 + fr;            // wave w owns rows w*16..+15
    int cur = 0;
    for (int q = 0; q < 10; ++q) {
        if (q < 9) LOADG(q + 1);
        #pragma unroll
        for (int ks = 0; ks < 4; ++ks) {
            int c = ks * 4 + fq;
            short8 a  = sA[cur][ra * 16 + (c ^ (ra & 15))];
            short8 q0 = sB[cur][fr * 16        + (c ^ fr)];
            short8 q1 = sB[cur][(16 + fr) * 16 + (c ^ fr)];
            short8 q2 = sB[cur][(32 + fr) * 16 + (c ^ fr)];
            acc0 = MFMA16(a, q0, acc0);
            acc1 = MFMA16(a, q1, acc1);
            acc2 = MFMA16(a, q2, acc2);
        }
        if (q < 9) WRITE(cur ^ 1);
        __syncthreads();
        cur ^= 1;
    }

    int h = hc * 16 + fr;
    float bb5 = cb5[h], bb3 = cb3[h], bb1 = cb1[h];
    float Linv = Linv_buf[b];
    #pragma unroll
    for (int j = 0; j < 4; ++j) {
        int row = row0 + w * 16 + fq * 4 + j;
        float t5 = fast_tanh(acc0[j] + bb5);
        float t3 = fast_tanh(acc1[j] + bb3);
        float t1 = fast_tanh(acc2[j] + bb1);
        float v = fmaxf(t1, fmaxf(t3, t5));
        cbf[row * HH + h] = __float2bfloat16(v);
        cm[row * HH + h] = v * (float)masks[row] * Linv;
    }
}

// ---- g0/g1 GEMM (M=2048,K=256,N=512); writes E = exp2(-log2e*(v+bias)) ----
__global__ __launch_bounds__(256, 2) void gemm_g_mfma_kernel(
        const __hip_bfloat16* __restrict__ cbf,
        const __hip_bfloat16* __restrict__ W01T,
        const float* __restrict__ b0, const float* __restrict__ b1v,
        float* __restrict__ E0, float* __restrict__ E1) {
    int blk = blockIdx.x;            // 64 m-tiles * 8 n-tiles = 512
    int by = blk >> 3, bx = blk & 7;
    int tid = threadIdx.x;
    int w = tid >> 6, lane = tid & 63;
    int wr = w >> 1, wc = w & 1;
    int m0 = by * 32 + wr * 16;
    int n0 = bx * 64 + wc * 32;
    int fr = lane & 15, fq = lane >> 4;

    const short8* ap = (const short8*)(cbf + (m0 + fr) * HH + fq * 8);
    const short8* bptr0 = (const short8*)(W01T + (n0 + fr) * HH + fq * 8);
    const short8* bptr1 = (const short8*)(W01T + (n0 + 16 + fr) * HH + fq * 8);

    f32x4 acc[2] = {};
    #pragma unroll
    for (int ks = 0; ks < 8; ++ks) {
        short8 a = ap[ks * 4];
        acc[0] = MFMA16(a, bptr0[ks * 4], acc[0]);
        acc[1] = MFMA16(a, bptr1[ks * 4], acc[1]);
    }
    #pragma unroll
    for (int n = 0; n < 2; ++n) {
        int col = n0 + n * 16 + fr;
        float bias = (col < 256) ? b0[col] : b1v[col - 256];
        float* dst = (col < 256) ? (E0 + col) : (E1 + col - 256);
        #pragma unroll
        for (int j = 0; j < 4; ++j) {
            int row = m0 + fq * 4 + j;
            dst[row * HH] = fast_exp2(NLOG2E * (acc[n][j] + bias));
        }
    }
}

// ---- fused relation + projection + softmax ---------------------------------
// block = (b, 4 i-rows); threads = h. Full j-sum, then Wo-proj + softmax.
__global__ __launch_bounds__(256) void relation_final_kernel(
        const float* __restrict__ E0, const float* __restrict__ E1,
        const float* __restrict__ cm, const int* __restrict__ masks,
        const float* __restrict__ Wo, const float* __restrict__ bo,
        float* __restrict__ out) {
    int blk = blockIdx.x;            // b*64 + iq
    int b = blk >> 6;
    int i0 = (blk & 63) * 4;
    int h = threadIdx.x;

    __shared__ float rel_lds[4][HH];
    __shared__ float lg[4][NTAGS];

    float e0t[4], acc[4];
    #pragma unroll
    for (int t = 0; t < 4; ++t) {
        e0t[t] = E0[(b * SS + i0 + t) * HH + h];
        acc[t] = 0.f;
    }
    const float* e1b = E1 + b * SS * HH + h;
    const float* cmb = cm + b * SS * HH + h;
    #pragma unroll 4
    for (int j = 0; j < SS; ++j) {
        float e1 = e1b[j * HH];
        float cv = cmb[j * HH];
        #pragma unroll
        for (int t = 0; t < 4; ++t)
            acc[t] = fmaf(fast_rcp(fmaf(e0t[t], e1, 1.0f)), cv, acc[t]);
    }
    #pragma unroll
    for (int t = 0; t < 4; ++t) {
        float mi = (float)masks[b * SS + i0 + t];
        rel_lds[t][h] = fast_tanh(acc[t] * mi);
    }
    __syncthreads();

    // projection: 4 warps x 3 h-slices x 17 tags
    int grp = h >> 6, lane = h & 63;
    int p = lane / 17, tg = lane % 17;
    float lacc = 0.f;
    if (p < 3) {
        const float* rrow = rel_lds[grp];
        int hb = p * 85, he = (p == 2) ? 256 : (p * 85 + 85);
        for (int hh = hb; hh < he; ++hh)
            lacc = fmaf(rrow[hh], Wo[hh * NTAGS + tg], lacc);
    }
    float v1 = __shfl(lacc, tg + 17, 64);
    float v2 = __shfl(lacc, tg + 34, 64);
    if (lane < NTAGS) lg[grp][lane] = lacc + v1 + v2 + bo[lane];
    __syncthreads();

    if (h < 4) {
        float mx = -1e30f;
        #pragma unroll
        for (int t = 0; t < NTAGS; ++t) mx = fmaxf(mx, lg[h][t]);
        float ex[NTAGS], sum = 0.f;
        #pragma unroll
        for (int t = 0; t < NTAGS; ++t) { ex[t] = __expf(lg[h][t] - mx); sum += ex[t]; }
        float si = fast_rcp(sum);
        int ii = i0 + h;
        #pragma unroll
        for (int t = 0; t < NTAGS; ++t)
            out[(b * SS + ii) * NTAGS + t] = ex[t] * si;
    }
}

extern "C" void kernel_launch(void* const* d_in, const int* in_sizes, int n_in,
                              void* d_out, int out_size, void* d_ws, size_t ws_size,
                              hipStream_t stream) {
    const int*   tokens     = (const int*)d_in[0];
    const int*   masks      = (const int*)d_in[1];
    const float* char_emb   = (const float*)d_in[2];
    const float* bigram_emb = (const float*)d_in[3];
    const float* conv1_w    = (const float*)d_in[4];
    const float* conv1_b    = (const float*)d_in[5];
    const float* conv3_w    = (const float*)d_in[6];
    const float* conv3_b    = (const float*)d_in[7];
    const float* conv5_w    = (const float*)d_in[8];
    const float* conv5_b    = (const float*)d_in[9];
    const float* W0         = (const float*)d_in[10];
    const float* b0         = (const float*)d_in[11];
    const float* W1         = (const float*)d_in[12];
    const float* b1         = (const float*)d_in[13];
    const float* Wo         = (const float*)d_in[14];
    const float* bo         = (const float*)d_in[15];
    float* out = (float*)d_out;

    char* p = (char*)d_ws;
    __hip_bfloat16* xbf    = (__hip_bfloat16*)p;  p += BB * SPAD * EMBED * 2;   // 1.06 MB
    __hip_bfloat16* WcombT = (__hip_bfloat16*)p;  p += 768 * 1280 * 2;          // 1.97 MB
    __hip_bfloat16* W01T   = (__hip_bfloat16*)p;  p += 512 * 256 * 2;           // 0.26 MB
    __hip_bfloat16* cbf    = (__hip_bfloat16*)p;  p += NROWS * HH * 2;          // 1.05 MB
    float* cm  = (float*)p;  p += (size_t)NROWS * HH * 4;                       // 2.1 MB
    float* E0  = (float*)p;  p += (size_t)NROWS * HH * 4;                       // 2.1 MB
    float* E1  = (float*)p;  p += (size_t)NROWS * HH * 4;                       // 2.1 MB
    float* Linv_buf = (float*)p;  p += 64;

    embed_pack_kernel<<<BB * SPAD + 160 + 256 + 1, 256, 0, stream>>>(
        tokens, char_emb, bigram_emb, conv1_w, conv3_w, conv5_w, W0, W1,
        masks, xbf, WcombT, W01T, Linv_buf);
    conv_mfma_fused<<<512, 256, 0, stream>>>(xbf, WcombT, conv1_b, conv3_b,
                                             conv5_b, masks, Linv_buf, cbf, cm);
    gemm_g_mfma_kernel<<<512, 256, 0, stream>>>(cbf, W01T, b0, b1, E0, E1);
    relation_final_kernel<<<BB * 64, 256, 0, stream>>>(E0, E1, cm, masks, Wo, bo, out);
}

// Round 9
// 61.023 us; speedup vs baseline: 1.5790x; 1.3015x over previous
//
#include <hip/hip_runtime.h>
#include <hip/hip_bf16.h>

#define BB 8
#define SS 256
#define CHAR_E 128
#define BI_E 64
#define EMBED 256
#define HH 256
#define NTAGS 17
#define SPAD 260   // S + 2 zero-pad rows each side
#define NROWS 2048 // B*S
#define NLOG2E -1.4426950408889634f

typedef __attribute__((ext_vector_type(8))) short short8;
typedef __attribute__((ext_vector_type(4))) float f32x4;
typedef __attribute__((ext_vector_type(2))) float f32x2;
#define MFMA16(a, b, c) __builtin_amdgcn_mfma_f32_16x16x32_bf16(a, b, c, 0, 0, 0)

__device__ __forceinline__ float fast_rcp(float x) {
    return __builtin_amdgcn_rcpf(x);
}
__device__ __forceinline__ float fast_exp2(float x) {
    return __builtin_amdgcn_exp2f(x);
}
__device__ __forceinline__ float fast_tanh(float x) {
    float e = __expf(2.0f * x);
    return 1.0f - 2.0f * fast_rcp(e + 1.0f);
}

// ---- fused: embed gather -> xbf; pack WcombT/W01T; lengths -----------------
__global__ __launch_bounds__(256) void embed_pack_kernel(
        const int* __restrict__ tokens,
        const float* __restrict__ char_emb,
        const float* __restrict__ bigram_emb,
        const float* __restrict__ w1, const float* __restrict__ w3,
        const float* __restrict__ w5,
        const float* __restrict__ W0, const float* __restrict__ W1mat,
        const int* __restrict__ masks,
        __hip_bfloat16* __restrict__ xbf,
        __hip_bfloat16* __restrict__ WcombT,
        __hip_bfloat16* __restrict__ W01T,
        float* __restrict__ Linv_buf) {
    int blk = blockIdx.x;
    int t = threadIdx.x;
    if (blk < BB * SPAD) {
        int b = blk / SPAD, r = blk % SPAD;
        float v = 0.0f;
        if (r >= 2 && r < SS + 2) {
            int s = r - 2;
            const int* tk = tokens + (b * SS + s) * 3;
            if (t < CHAR_E)              v = char_emb[tk[0] * CHAR_E + t];
            else if (t < CHAR_E + BI_E)  v = bigram_emb[tk[1] * BI_E + (t - CHAR_E)];
            else                         v = bigram_emb[tk[2] * BI_E + (t - CHAR_E - BI_E)];
        }
        xbf[blk * EMBED + t] = __float2bfloat16(v);
    } else if (blk < BB * SPAD + 160) {
        // WcombT pack: block = 8 kk-cols, thread = h; short8 (16B) stores
        int kk0 = (blk - BB * SPAD) * 8;
        int h = t, hc = h >> 4, hl = h & 15;
        union { short8 v; __hip_bfloat16 b[8]; } u5, u3, u1;
        #pragma unroll
        for (int k = 0; k < 8; ++k) {
            int kk = kk0 + k, tap = kk >> 8, e = kk & 255;
            float f5 = w5[(tap * EMBED + e) * HH + h];
            float f3 = (tap >= 1 && tap <= 3) ? w3[((tap - 1) * EMBED + e) * HH + h] : 0.f;
            float f1 = (tap == 2) ? w1[e * HH + h] : 0.f;
            u5.b[k] = __float2bfloat16(f5);
            u3.b[k] = __float2bfloat16(f3);
            u1.b[k] = __float2bfloat16(f1);
        }
        *(short8*)(WcombT + (hc * 48 +  0 + hl) * 1280 + kk0) = u5.v;
        *(short8*)(WcombT + (hc * 48 + 16 + hl) * 1280 + kk0) = u3.v;
        *(short8*)(WcombT + (hc * 48 + 32 + hl) * 1280 + kk0) = u1.v;
    } else if (blk < BB * SPAD + 160 + 256) {
        // W01T pack: block = e, threads = h (reads coalesced over h)
        int e = blk - BB * SPAD - 160;
        W01T[t * 256 + e]         = __float2bfloat16(W0[e * HH + t]);
        W01T[(256 + t) * 256 + e] = __float2bfloat16(W1mat[e * HH + t]);
    } else {
        // lengths: b = t>>5, 32 lanes each sum 8 masks, shuffle-reduce
        int b = t >> 5, l = t & 31;
        int ssum = 0;
        #pragma unroll
        for (int k = 0; k < 8; ++k) ssum += masks[b * SS + l * 8 + k];
        #pragma unroll
        for (int o = 16; o; o >>= 1) ssum += __shfl_xor(ssum, o);
        if (l == 0) Linv_buf[b] = (ssum > 0) ? (1.0f / (float)ssum) : 0.0f;
    }
}

// ---- conv as LDS-tiled MFMA GEMM (BM=64, BN=48, BK=128, dbuf) --------------
// Epilogue: tanh+max -> cbf[row][h] (bf16) and cmT[h][row] = c*m*Linv (f32).
__global__ __launch_bounds__(256, 2) void conv_mfma_fused(
        const __hip_bfloat16* __restrict__ xbf,
        const __hip_bfloat16* __restrict__ WcombT,
        const float* __restrict__ cb1, const float* __restrict__ cb3,
        const float* __restrict__ cb5,
        const int* __restrict__ masks, const float* __restrict__ Linv_buf,
        __hip_bfloat16* __restrict__ cbf, float* __restrict__ cmT) {
    __shared__ short8 sA[2][1024];   // [64 rows][16 chunks], 16KB per buf
    __shared__ short8 sB[2][768];    // [48 rows][16 chunks], 12KB per buf

    int blk = blockIdx.x;            // mt*16 + hc
    int mt = blk >> 4, hc = blk & 15;
    int tid = threadIdx.x, w = tid >> 6, lane = tid & 63;
    int fr = lane & 15, fq = lane >> 4;
    int row0 = mt * 64;
    int b = row0 >> 8, s0 = row0 & 255;
    const __hip_bfloat16* xbase = xbf + (b * SPAD + s0) * EMBED;
    const __hip_bfloat16* wbase = WcombT + (hc * 48) * 1280;

    short8 va[4], vb[3];
    auto LOADG = [&](int q) {
        int tap = q >> 1, e0 = (q & 1) * 128;
        const __hip_bfloat16* xs = xbase + tap * EMBED + e0;
        #pragma unroll
        for (int it = 0; it < 4; ++it) {
            int s = tid + it * 256, r = s >> 4, cg = s & 15;
            va[it] = *(const short8*)(xs + r * EMBED + cg * 8);
        }
        const __hip_bfloat16* wsrc = wbase + q * 128;
        #pragma unroll
        for (int it = 0; it < 3; ++it) {
            int s = tid + it * 256, r = s >> 4, cg = s & 15;
            vb[it] = *(const short8*)(wsrc + r * 1280 + cg * 8);
        }
    };
    auto WRITE = [&](int buf) {
        #pragma unroll
        for (int it = 0; it < 4; ++it) {
            int s = tid + it * 256, r = s >> 4, cg = s & 15;
            sA[buf][r * 16 + (cg ^ (r & 15))] = va[it];
        }
        #pragma unroll
        for (int it = 0; it < 3; ++it) {
            int s = tid + it * 256, r = s >> 4, cg = s & 15;
            sB[buf][r * 16 + (cg ^ (r & 15))] = vb[it];
        }
    };

    LOADG(0);
    WRITE(0);
    __syncthreads();

    f32x4 acc0 = {}, acc1 = {}, acc2 = {};
    int ra = w * 16 + fr;            // wave w owns rows w*16..+15
    int cur = 0;
    for (int q = 0; q < 10; ++q) {
        if (q < 9) LOADG(q + 1);
        #pragma unroll
        for (int ks = 0; ks < 4; ++ks) {
            int c = ks * 4 + fq;
            short8 a  = sA[cur][ra * 16 + (c ^ (ra & 15))];
            short8 q0 = sB[cur][fr * 16        + (c ^ fr)];
            short8 q1 = sB[cur][(16 + fr) * 16 + (c ^ fr)];
            short8 q2 = sB[cur][(32 + fr) * 16 + (c ^ fr)];
            acc0 = MFMA16(a, q0, acc0);
            acc1 = MFMA16(a, q1, acc1);
            acc2 = MFMA16(a, q2, acc2);
        }
        if (q < 9) WRITE(cur ^ 1);
        __syncthreads();
        cur ^= 1;
    }

    int h = hc * 16 + fr;
    float bb5 = cb5[h], bb3 = cb3[h], bb1 = cb1[h];
    float Linv = Linv_buf[b];
    #pragma unroll
    for (int j = 0; j < 4; ++j) {
        int row = row0 + w * 16 + fq * 4 + j;
        float t5 = fast_tanh(acc0[j] + bb5);
        float t3 = fast_tanh(acc1[j] + bb3);
        float t1 = fast_tanh(acc2[j] + bb1);
        float v = fmaxf(t1, fmaxf(t3, t5));
        cbf[row * HH + h] = __float2bfloat16(v);
        cmT[h * NROWS + row] = v * (float)masks[row] * Linv;
    }
}

// ---- g0/g1 GEMM; writes E = exp2(-log2e*(v+bias)) TRANSPOSED [h][row] ------
__global__ __launch_bounds__(256, 2) void gemm_g_mfma_kernel(
        const __hip_bfloat16* __restrict__ cbf,
        const __hip_bfloat16* __restrict__ W01T,
        const float* __restrict__ b0, const float* __restrict__ b1v,
        float* __restrict__ E0T, float* __restrict__ E1T) {
    int blk = blockIdx.x;            // 64 m-tiles * 8 n-tiles = 512
    int by = blk >> 3, bx = blk & 7;
    int tid = threadIdx.x;
    int w = tid >> 6, lane = tid & 63;
    int wr = w >> 1, wc = w & 1;
    int m0 = by * 32 + wr * 16;
    int n0 = bx * 64 + wc * 32;
    int fr = lane & 15, fq = lane >> 4;

    const short8* ap = (const short8*)(cbf + (m0 + fr) * HH + fq * 8);
    const short8* bptr0 = (const short8*)(W01T + (n0 + fr) * HH + fq * 8);
    const short8* bptr1 = (const short8*)(W01T + (n0 + 16 + fr) * HH + fq * 8);

    f32x4 acc[2] = {};
    #pragma unroll
    for (int ks = 0; ks < 8; ++ks) {
        short8 a = ap[ks * 4];
        acc[0] = MFMA16(a, bptr0[ks * 4], acc[0]);
        acc[1] = MFMA16(a, bptr1[ks * 4], acc[1]);
    }
    #pragma unroll
    for (int n = 0; n < 2; ++n) {
        int col = n0 + n * 16 + fr;
        float bias = (col < 256) ? b0[col] : b1v[col - 256];
        float* dst = (col < 256) ? (E0T + col * NROWS)
                                 : (E1T + (col - 256) * NROWS);
        #pragma unroll
        for (int j = 0; j < 4; ++j) {
            int row = m0 + fq * 4 + j;
            dst[row] = fast_exp2(NLOG2E * (acc[n][j] + bias));
        }
    }
}

// ---- relation: block=(b,h); threads=i; LDS j-loop; 100% occupancy ----------
// acc = sum_j rcp(1 + E0T[h][i]*E1T[h][j]) * cmT[h][j]; relT[h][row] out.
__global__ __launch_bounds__(256) void relation_kernel(
        const float* __restrict__ E0T, const float* __restrict__ E1T,
        const float* __restrict__ cmT, const int* __restrict__ masks,
        float* __restrict__ relT) {
    int blk = blockIdx.x;            // b*256 + h
    int b = blk >> 8, h = blk & 255;
    int i = threadIdx.x;
    int row = b * SS + i;

    __shared__ f32x2 ps[SS];         // {e1, cm} per j
    {
        f32x2 pv;
        pv[0] = E1T[h * NROWS + row];    // coalesced
        pv[1] = cmT[h * NROWS + row];    // coalesced
        ps[i] = pv;
    }
    __syncthreads();

    float e0 = E0T[h * NROWS + row];     // coalesced
    float acc = 0.f;
    #pragma unroll 8
    for (int j = 0; j < SS; ++j) {
        f32x2 v = ps[j];                 // uniform -> LDS broadcast
        acc = fmaf(fast_rcp(fmaf(e0, v[0], 1.0f)), v[1], acc);
    }
    float mi = (float)masks[row];
    relT[h * NROWS + row] = fast_tanh(acc * mi);   // coalesced
}

// ---- final: relT @ Wo + bo -> softmax -> out -------------------------------
__global__ __launch_bounds__(256) void final_kernel(
        const float* __restrict__ relT,
        const float* __restrict__ Wo, const float* __restrict__ bo,
        float* __restrict__ out) {
    int blk = blockIdx.x;            // b*64 + iblk
    int b = blk >> 6;
    int i0 = (blk & 63) * 4;
    int tid = threadIdx.x;

    __shared__ float lg[4][NTAGS];

    int grp = tid >> 6, lane = tid & 63;
    int row = b * SS + i0 + grp;
    int p = lane / 17, tg = lane % 17;
    float lacc = 0.f;
    if (p < 3) {
        int hb = p * 85, he = (p == 2) ? 256 : (p * 85 + 85);
        #pragma unroll 8
        for (int hh = hb; hh < he; ++hh)
            lacc = fmaf(relT[hh * NROWS + row], Wo[hh * NTAGS + tg], lacc);
    }
    float v1 = __shfl(lacc, tg + 17, 64);
    float v2 = __shfl(lacc, tg + 34, 64);
    if (lane < NTAGS) lg[grp][lane] = lacc + v1 + v2 + bo[lane];
    __syncthreads();

    if (tid < 4) {
        float mx = -1e30f;
        #pragma unroll
        for (int t = 0; t < NTAGS; ++t) mx = fmaxf(mx, lg[tid][t]);
        float ex[NTAGS], sum = 0.f;
        #pragma unroll
        for (int t = 0; t < NTAGS; ++t) { ex[t] = __expf(lg[tid][t] - mx); sum += ex[t]; }
        float si = fast_rcp(sum);
        int ii = i0 + tid;
        #pragma unroll
        for (int t = 0; t < NTAGS; ++t)
            out[(b * SS + ii) * NTAGS + t] = ex[t] * si;
    }
}

extern "C" void kernel_launch(void* const* d_in, const int* in_sizes, int n_in,
                              void* d_out, int out_size, void* d_ws, size_t ws_size,
                              hipStream_t stream) {
    const int*   tokens     = (const int*)d_in[0];
    const int*   masks      = (const int*)d_in[1];
    const float* char_emb   = (const float*)d_in[2];
    const float* bigram_emb = (const float*)d_in[3];
    const float* conv1_w    = (const float*)d_in[4];
    const float* conv1_b    = (const float*)d_in[5];
    const float* conv3_w    = (const float*)d_in[6];
    const float* conv3_b    = (const float*)d_in[7];
    const float* conv5_w    = (const float*)d_in[8];
    const float* conv5_b    = (const float*)d_in[9];
    const float* W0         = (const float*)d_in[10];
    const float* b0         = (const float*)d_in[11];
    const float* W1         = (const float*)d_in[12];
    const float* b1         = (const float*)d_in[13];
    const float* Wo         = (const float*)d_in[14];
    const float* bo         = (const float*)d_in[15];
    float* out = (float*)d_out;

    char* p = (char*)d_ws;
    __hip_bfloat16* xbf    = (__hip_bfloat16*)p;  p += BB * SPAD * EMBED * 2;   // 1.06 MB
    __hip_bfloat16* WcombT = (__hip_bfloat16*)p;  p += 768 * 1280 * 2;          // 1.97 MB
    __hip_bfloat16* W01T   = (__hip_bfloat16*)p;  p += 512 * 256 * 2;           // 0.26 MB
    __hip_bfloat16* cbf    = (__hip_bfloat16*)p;  p += NROWS * HH * 2;          // 1.05 MB
    float* cmT  = (float*)p;  p += (size_t)HH * NROWS * 4;                      // 2.1 MB
    float* E0T  = (float*)p;  p += (size_t)HH * NROWS * 4;                      // 2.1 MB
    float* E1T  = (float*)p;  p += (size_t)HH * NROWS * 4;                      // 2.1 MB
    float* relT = (float*)p;  p += (size_t)HH * NROWS * 4;                      // 2.1 MB
    float* Linv_buf = (float*)p;  p += 64;

    embed_pack_kernel<<<BB * SPAD + 160 + 256 + 1, 256, 0, stream>>>(
        tokens, char_emb, bigram_emb, conv1_w, conv3_w, conv5_w, W0, W1,
        masks, xbf, WcombT, W01T, Linv_buf);
    conv_mfma_fused<<<512, 256, 0, stream>>>(xbf, WcombT, conv1_b, conv3_b,
                                             conv5_b, masks, Linv_buf, cbf, cmT);
    gemm_g_mfma_kernel<<<512, 256, 0, stream>>>(cbf, W01T, b0, b1, E0T, E1T);
    relation_kernel<<<BB * 256, 256, 0, stream>>>(E0T, E1T, cmT, masks, relT);
    final_kernel<<<BB * 64, 256, 0, stream>>>(relT, Wo, bo, out);
}

// Round 13
// 60.990 us; speedup vs baseline: 1.5798x; 1.0005x over previous
//
#include <hip/hip_runtime.h>
#include <hip/hip_bf16.h>

#define BB 8
#define SS 256
#define CHAR_E 128
#define BI_E 64
#define EMBED 256
#define HH 256
#define NTAGS 17
#define SPAD 260   // S + 2 zero-pad rows each side
#define NROWS 2048 // B*S
#define NLOG2E -1.4426950408889634f

typedef __attribute__((ext_vector_type(8))) short short8;
typedef __attribute__((ext_vector_type(4))) float f32x4;
typedef __attribute__((ext_vector_type(2))) float f32x2;
#define MFMA16(a, b, c) __builtin_amdgcn_mfma_f32_16x16x32_bf16(a, b, c, 0, 0, 0)

__device__ __forceinline__ float fast_rcp(float x) {
    return __builtin_amdgcn_rcpf(x);
}
__device__ __forceinline__ float fast_exp2(float x) {
    return __builtin_amdgcn_exp2f(x);
}
__device__ __forceinline__ float fast_tanh(float x) {
    float e = __expf(2.0f * x);
    return 1.0f - 2.0f * fast_rcp(e + 1.0f);
}

// ---- fused: embed gather -> xbf; pack WcombT/W01T; lengths -----------------
__global__ __launch_bounds__(256) void embed_pack_kernel(
        const int* __restrict__ tokens,
        const float* __restrict__ char_emb,
        const float* __restrict__ bigram_emb,
        const float* __restrict__ w1, const float* __restrict__ w3,
        const float* __restrict__ w5,
        const float* __restrict__ W0, const float* __restrict__ W1mat,
        const int* __restrict__ masks,
        __hip_bfloat16* __restrict__ xbf,
        __hip_bfloat16* __restrict__ WcombT,
        __hip_bfloat16* __restrict__ W01T,
        float* __restrict__ Linv_buf) {
    int blk = blockIdx.x;
    int t = threadIdx.x;
    if (blk < BB * SPAD) {
        int b = blk / SPAD, r = blk % SPAD;
        float v = 0.0f;
        if (r >= 2 && r < SS + 2) {
            int s = r - 2;
            const int* tk = tokens + (b * SS + s) * 3;
            if (t < CHAR_E)              v = char_emb[tk[0] * CHAR_E + t];
            else if (t < CHAR_E + BI_E)  v = bigram_emb[tk[1] * BI_E + (t - CHAR_E)];
            else                         v = bigram_emb[tk[2] * BI_E + (t - CHAR_E - BI_E)];
        }
        xbf[blk * EMBED + t] = __float2bfloat16(v);
    } else if (blk < BB * SPAD + 160) {
        // WcombT pack: block = 8 kk-cols, thread = h; short8 (16B) stores
        int kk0 = (blk - BB * SPAD) * 8;
        int h = t, hc = h >> 4, hl = h & 15;
        union { short8 v; __hip_bfloat16 b[8]; } u5, u3, u1;
        #pragma unroll
        for (int k = 0; k < 8; ++k) {
            int kk = kk0 + k, tap = kk >> 8, e = kk & 255;
            float f5 = w5[(tap * EMBED + e) * HH + h];
            float f3 = (tap >= 1 && tap <= 3) ? w3[((tap - 1) * EMBED + e) * HH + h] : 0.f;
            float f1 = (tap == 2) ? w1[e * HH + h] : 0.f;
            u5.b[k] = __float2bfloat16(f5);
            u3.b[k] = __float2bfloat16(f3);
            u1.b[k] = __float2bfloat16(f1);
        }
        *(short8*)(WcombT + (hc * 48 +  0 + hl) * 1280 + kk0) = u5.v;
        *(short8*)(WcombT + (hc * 48 + 16 + hl) * 1280 + kk0) = u3.v;
        *(short8*)(WcombT + (hc * 48 + 32 + hl) * 1280 + kk0) = u1.v;
    } else if (blk < BB * SPAD + 160 + 256) {
        // W01T pack: block = e, threads = h (reads coalesced over h)
        int e = blk - BB * SPAD - 160;
        W01T[t * 256 + e]         = __float2bfloat16(W0[e * HH + t]);
        W01T[(256 + t) * 256 + e] = __float2bfloat16(W1mat[e * HH + t]);
    } else {
        // lengths: b = t>>5, 32 lanes each sum 8 masks, shuffle-reduce
        int b = t >> 5, l = t & 31;
        int ssum = 0;
        #pragma unroll
        for (int k = 0; k < 8; ++k) ssum += masks[b * SS + l * 8 + k];
        #pragma unroll
        for (int o = 16; o; o >>= 1) ssum += __shfl_xor(ssum, o);
        if (l == 0) Linv_buf[b] = (ssum > 0) ? (1.0f / (float)ssum) : 0.0f;
    }
}

// ---- conv as LDS-tiled MFMA GEMM (BM=64, BN=48, BK=128, dbuf) --------------
// Epilogue: tanh+max -> cbf[row][h] (bf16) and cmT[h][row] = c*m*Linv (f32).
__global__ __launch_bounds__(256, 2) void conv_mfma_fused(
        const __hip_bfloat16* __restrict__ xbf,
        const __hip_bfloat16* __restrict__ WcombT,
        const float* __restrict__ cb1, const float* __restrict__ cb3,
        const float* __restrict__ cb5,
        const int* __restrict__ masks, const float* __restrict__ Linv_buf,
        __hip_bfloat16* __restrict__ cbf, float* __restrict__ cmT) {
    __shared__ short8 sA[2][1024];   // [64 rows][16 chunks], 16KB per buf
    __shared__ short8 sB[2][768];    // [48 rows][16 chunks], 12KB per buf

    int blk = blockIdx.x;            // mt*16 + hc
    int mt = blk >> 4, hc = blk & 15;
    int tid = threadIdx.x, w = tid >> 6, lane = tid & 63;
    int fr = lane & 15, fq = lane >> 4;
    int row0 = mt * 64;
    int b = row0 >> 8, s0 = row0 & 255;
    const __hip_bfloat16* xbase = xbf + (b * SPAD + s0) * EMBED;
    const __hip_bfloat16* wbase = WcombT + (hc * 48) * 1280;

    short8 va[4], vb[3];
    auto LOADG = [&](int q) {
        int tap = q >> 1, e0 = (q & 1) * 128;
        const __hip_bfloat16* xs = xbase + tap * EMBED + e0;
        #pragma unroll
        for (int it = 0; it < 4; ++it) {
            int s = tid + it * 256, r = s >> 4, cg = s & 15;
            va[it] = *(const short8*)(xs + r * EMBED + cg * 8);
        }
        const __hip_bfloat16* wsrc = wbase + q * 128;
        #pragma unroll
        for (int it = 0; it < 3; ++it) {
            int s = tid + it * 256, r = s >> 4, cg = s & 15;
            vb[it] = *(const short8*)(wsrc + r * 1280 + cg * 8);
        }
    };
    auto WRITE = [&](int buf) {
        #pragma unroll
        for (int it = 0; it < 4; ++it) {
            int s = tid + it * 256, r = s >> 4, cg = s & 15;
            sA[buf][r * 16 + (cg ^ (r & 15))] = va[it];
        }
        #pragma unroll
        for (int it = 0; it < 3; ++it) {
            int s = tid + it * 256, r = s >> 4, cg = s & 15;
            sB[buf][r * 16 + (cg ^ (r & 15))] = vb[it];
        }
    };

    LOADG(0);
    WRITE(0);
    __syncthreads();

    f32x4 acc0 = {}, acc1 = {}, acc2 = {};
    int ra = w * 16 + fr;            // wave w owns rows w*16..+15
    int cur = 0;
    for (int q = 0; q < 10; ++q) {
        if (q < 9) LOADG(q + 1);
        #pragma unroll
        for (int ks = 0; ks < 4; ++ks) {
            int c = ks * 4 + fq;
            short8 a  = sA[cur][ra * 16 + (c ^ (ra & 15))];
            short8 q0 = sB[cur][fr * 16        + (c ^ fr)];
            short8 q1 = sB[cur][(16 + fr) * 16 + (c ^ fr)];
            short8 q2 = sB[cur][(32 + fr) * 16 + (c ^ fr)];
            acc0 = MFMA16(a, q0, acc0);
            acc1 = MFMA16(a, q1, acc1);
            acc2 = MFMA16(a, q2, acc2);
        }
        if (q < 9) WRITE(cur ^ 1);
        __syncthreads();
        cur ^= 1;
    }

    int h = hc * 16 + fr;
    float bb5 = cb5[h], bb3 = cb3[h], bb1 = cb1[h];
    float Linv = Linv_buf[b];
    #pragma unroll
    for (int j = 0; j < 4; ++j) {
        int row = row0 + w * 16 + fq * 4 + j;
        float t5 = fast_tanh(acc0[j] + bb5);
        float t3 = fast_tanh(acc1[j] + bb3);
        float t1 = fast_tanh(acc2[j] + bb1);
        float v = fmaxf(t1, fmaxf(t3, t5));
        cbf[row * HH + h] = __float2bfloat16(v);
        cmT[h * NROWS + row] = v * (float)masks[row] * Linv;
    }
}

// ---- g0/g1 GEMM; writes E = exp2(-log2e*(v+bias)) TRANSPOSED [h][row] ------
__global__ __launch_bounds__(256, 2) void gemm_g_mfma_kernel(
        const __hip_bfloat16* __restrict__ cbf,
        const __hip_bfloat16* __restrict__ W01T,
        const float* __restrict__ b0, const float* __restrict__ b1v,
        float* __restrict__ E0T, float* __restrict__ E1T) {
    int blk = blockIdx.x;            // 64 m-tiles * 8 n-tiles = 512
    int by = blk >> 3, bx = blk & 7;
    int tid = threadIdx.x;
    int w = tid >> 6, lane = tid & 63;
    int wr = w >> 1, wc = w & 1;
    int m0 = by * 32 + wr * 16;
    int n0 = bx * 64 + wc * 32;
    int fr = lane & 15, fq = lane >> 4;

    const short8* ap = (const short8*)(cbf + (m0 + fr) * HH + fq * 8);
    const short8* bptr0 = (const short8*)(W01T + (n0 + fr) * HH + fq * 8);
    const short8* bptr1 = (const short8*)(W01T + (n0 + 16 + fr) * HH + fq * 8);

    f32x4 acc[2] = {};
    #pragma unroll
    for (int ks = 0; ks < 8; ++ks) {
        short8 a = ap[ks * 4];
        acc[0] = MFMA16(a, bptr0[ks * 4], acc[0]);
        acc[1] = MFMA16(a, bptr1[ks * 4], acc[1]);
    }
    #pragma unroll
    for (int n = 0; n < 2; ++n) {
        int col = n0 + n * 16 + fr;
        float bias = (col < 256) ? b0[col] : b1v[col - 256];
        float* dst = (col < 256) ? (E0T + col * NROWS)
                                 : (E1T + (col - 256) * NROWS);
        #pragma unroll
        for (int j = 0; j < 4; ++j) {
            int row = m0 + fq * 4 + j;
            dst[row] = fast_exp2(NLOG2E * (acc[n][j] + bias));
        }
    }
}

// ---- relation: block=(b,h); threads=i; LDS j-loop; 100% occupancy ----------
__global__ __launch_bounds__(256) void relation_kernel(
        const float* __restrict__ E0T, const float* __restrict__ E1T,
        const float* __restrict__ cmT, const int* __restrict__ masks,
        float* __restrict__ relT) {
    int blk = blockIdx.x;            // b*256 + h
    int b = blk >> 8, h = blk & 255;
    int i = threadIdx.x;
    int row = b * SS + i;

    __shared__ f32x2 ps[SS];         // {e1, cm} per j
    {
        f32x2 pv;
        pv[0] = E1T[h * NROWS + row];    // coalesced
        pv[1] = cmT[h * NROWS + row];    // coalesced
        ps[i] = pv;
    }
    __syncthreads();

    float e0 = E0T[h * NROWS + row];     // coalesced
    float acc = 0.f;
    #pragma unroll 8
    for (int j = 0; j < SS; ++j) {
        f32x2 v = ps[j];                 // uniform -> LDS broadcast
        acc = fmaf(fast_rcp(fmaf(e0, v[0], 1.0f)), v[1], acc);
    }
    float mi = (float)masks[row];
    relT[h * NROWS + row] = fast_tanh(acc * mi);   // coalesced
}

// ---- final: relT @ Wo + bo -> softmax -> out -------------------------------
__global__ __launch_bounds__(256) void final_kernel(
        const float* __restrict__ relT,
        const float* __restrict__ Wo, const float* __restrict__ bo,
        float* __restrict__ out) {
    int blk = blockIdx.x;            // b*64 + iblk
    int b = blk >> 6;
    int i0 = (blk & 63) * 4;
    int tid = threadIdx.x;

    __shared__ float lg[4][NTAGS];

    int grp = tid >> 6, lane = tid & 63;
    int row = b * SS + i0 + grp;
    int p = lane / 17, tg = lane % 17;
    float lacc = 0.f;
    if (p < 3) {
        int hb = p * 85, he = (p == 2) ? 256 : (p * 85 + 85);
        #pragma unroll 8
        for (int hh = hb; hh < he; ++hh)
            lacc = fmaf(relT[hh * NROWS + row], Wo[hh * NTAGS + tg], lacc);
    }
    float v1 = __shfl(lacc, tg + 17, 64);
    float v2 = __shfl(lacc, tg + 34, 64);
    if (lane < NTAGS) lg[grp][lane] = lacc + v1 + v2 + bo[lane];
    __syncthreads();

    if (tid < 4) {
        float mx = -1e30f;
        #pragma unroll
        for (int t = 0; t < NTAGS; ++t) mx = fmaxf(mx, lg[tid][t]);
        float ex[NTAGS], sum = 0.f;
        #pragma unroll
        for (int t = 0; t < NTAGS; ++t) { ex[t] = __expf(lg[tid][t] - mx); sum += ex[t]; }
        float si = fast_rcp(sum);
        int ii = i0 + tid;
        #pragma unroll
        for (int t = 0; t < NTAGS; ++t)
            out[(b * SS + ii) * NTAGS + t] = ex[t] * si;
    }
}

extern "C" void kernel_launch(void* const* d_in, const int* in_sizes, int n_in,
                              void* d_out, int out_size, void* d_ws, size_t ws_size,
                              hipStream_t stream) {
    const int*   tokens     = (const int*)d_in[0];
    const int*   masks      = (const int*)d_in[1];
    const float* char_emb   = (const float*)d_in[2];
    const float* bigram_emb = (const float*)d_in[3];
    const float* conv1_w    = (const float*)d_in[4];
    const float* conv1_b    = (const float*)d_in[5];
    const float* conv3_w    = (const float*)d_in[6];
    const float* conv3_b    = (const float*)d_in[7];
    const float* conv5_w    = (const float*)d_in[8];
    const float* conv5_b    = (const float*)d_in[9];
    const float* W0         = (const float*)d_in[10];
    const float* b0         = (const float*)d_in[11];
    const float* W1         = (const float*)d_in[12];
    const float* b1         = (const float*)d_in[13];
    const float* Wo         = (const float*)d_in[14];
    const float* bo         = (const float*)d_in[15];
    float* out = (float*)d_out;

    char* p = (char*)d_ws;
    __hip_bfloat16* xbf    = (__hip_bfloat16*)p;  p += BB * SPAD * EMBED * 2;   // 1.06 MB
    __hip_bfloat16* WcombT = (__hip_bfloat16*)p;  p += 768 * 1280 * 2;          // 1.97 MB
    __hip_bfloat16* W01T   = (__hip_bfloat16*)p;  p += 512 * 256 * 2;           // 0.26 MB
    __hip_bfloat16* cbf    = (__hip_bfloat16*)p;  p += NROWS * HH * 2;          // 1.05 MB
    float* cmT  = (float*)p;  p += (size_t)HH * NROWS * 4;                      // 2.1 MB
    float* E0T  = (float*)p;  p += (size_t)HH * NROWS * 4;                      // 2.1 MB
    float* E1T  = (float*)p;  p += (size_t)HH * NROWS * 4;                      // 2.1 MB
    float* relT = (float*)p;  p += (size_t)HH * NROWS * 4;                      // 2.1 MB
    float* Linv_buf = (float*)p;  p += 64;

    embed_pack_kernel<<<BB * SPAD + 160 + 256 + 1, 256, 0, stream>>>(
        tokens, char_emb, bigram_emb, conv1_w, conv3_w, conv5_w, W0, W1,
        masks, xbf, WcombT, W01T, Linv_buf);
    conv_mfma_fused<<<512, 256, 0, stream>>>(xbf, WcombT, conv1_b, conv3_b,
                                             conv5_b, masks, Linv_buf, cbf, cmT);
    gemm_g_mfma_kernel<<<512, 256, 0, stream>>>(cbf, W01T, b0, b1, E0T, E1T);
    relation_kernel<<<BB * 256, 256, 0, stream>>>(E0T, E1T, cmT, masks, relT);
    final_kernel<<<BB * 64, 256, 0, stream>>>(relT, Wo, bo, out);
}

// Round 14
// 58.971 us; speedup vs baseline: 1.6339x; 1.0342x over previous
//
#include <hip/hip_runtime.h>
#include <hip/hip_bf16.h>

#define BB 8
#define SS 256
#define CHAR_E 128
#define BI_E 64
#define EMBED 256
#define HH 256
#define NTAGS 17
#define SPAD 260   // S + 2 zero-pad rows each side
#define NROWS 2048 // B*S
#define NLOG2E -1.4426950408889634f

typedef __attribute__((ext_vector_type(8))) short short8;
typedef __attribute__((ext_vector_type(4))) float f32x4;
typedef __attribute__((ext_vector_type(2))) float f32x2;
#define MFMA16(a, b, c) __builtin_amdgcn_mfma_f32_16x16x32_bf16(a, b, c, 0, 0, 0)

__device__ __forceinline__ float fast_rcp(float x) {
    return __builtin_amdgcn_rcpf(x);
}
__device__ __forceinline__ float fast_exp2(float x) {
    return __builtin_amdgcn_exp2f(x);
}
__device__ __forceinline__ float fast_tanh(float x) {
    float e = __expf(2.0f * x);
    return 1.0f - 2.0f * fast_rcp(e + 1.0f);
}

// ---- fused: embed gather -> xbf; pack WcombT/W01T; lengths -----------------
__global__ __launch_bounds__(256) void embed_pack_kernel(
        const int* __restrict__ tokens,
        const float* __restrict__ char_emb,
        const float* __restrict__ bigram_emb,
        const float* __restrict__ w1, const float* __restrict__ w3,
        const float* __restrict__ w5,
        const float* __restrict__ W0, const float* __restrict__ W1mat,
        const int* __restrict__ masks,
        __hip_bfloat16* __restrict__ xbf,
        __hip_bfloat16* __restrict__ WcombT,
        __hip_bfloat16* __restrict__ W01T,
        float* __restrict__ Linv_buf) {
    int blk = blockIdx.x;
    int t = threadIdx.x;
    if (blk < BB * SPAD) {
        int b = blk / SPAD, r = blk % SPAD;
        float v = 0.0f;
        if (r >= 2 && r < SS + 2) {
            int s = r - 2;
            const int* tk = tokens + (b * SS + s) * 3;
            if (t < CHAR_E)              v = char_emb[tk[0] * CHAR_E + t];
            else if (t < CHAR_E + BI_E)  v = bigram_emb[tk[1] * BI_E + (t - CHAR_E)];
            else                         v = bigram_emb[tk[2] * BI_E + (t - CHAR_E - BI_E)];
        }
        xbf[blk * EMBED + t] = __float2bfloat16(v);
    } else if (blk < BB * SPAD + 160) {
        // WcombT pack: block = 8 kk-cols, thread = h; short8 (16B) stores
        int kk0 = (blk - BB * SPAD) * 8;
        int h = t, hc = h >> 4, hl = h & 15;
        union { short8 v; __hip_bfloat16 b[8]; } u5, u3, u1;
        #pragma unroll
        for (int k = 0; k < 8; ++k) {
            int kk = kk0 + k, tap = kk >> 8, e = kk & 255;
            float f5 = w5[(tap * EMBED + e) * HH + h];
            float f3 = (tap >= 1 && tap <= 3) ? w3[((tap - 1) * EMBED + e) * HH + h] : 0.f;
            float f1 = (tap == 2) ? w1[e * HH + h] : 0.f;
            u5.b[k] = __float2bfloat16(f5);
            u3.b[k] = __float2bfloat16(f3);
            u1.b[k] = __float2bfloat16(f1);
        }
        *(short8*)(WcombT + (hc * 48 +  0 + hl) * 1280 + kk0) = u5.v;
        *(short8*)(WcombT + (hc * 48 + 16 + hl) * 1280 + kk0) = u3.v;
        *(short8*)(WcombT + (hc * 48 + 32 + hl) * 1280 + kk0) = u1.v;
    } else if (blk < BB * SPAD + 160 + 256) {
        // W01T pack: block = e, threads = h (reads coalesced over h)
        int e = blk - BB * SPAD - 160;
        W01T[t * 256 + e]         = __float2bfloat16(W0[e * HH + t]);
        W01T[(256 + t) * 256 + e] = __float2bfloat16(W1mat[e * HH + t]);
    } else {
        // lengths: b = t>>5, 32 lanes each sum 8 masks, shuffle-reduce
        int b = t >> 5, l = t & 31;
        int ssum = 0;
        #pragma unroll
        for (int k = 0; k < 8; ++k) ssum += masks[b * SS + l * 8 + k];
        #pragma unroll
        for (int o = 16; o; o >>= 1) ssum += __shfl_xor(ssum, o);
        if (l == 0) Linv_buf[b] = (ssum > 0) ? (1.0f / (float)ssum) : 0.0f;
    }
}

// ---- conv as LDS-tiled MFMA GEMM (BM=64, BN=48, BK=128, dbuf) --------------
// Epilogue: tanh+max -> cbf[row][h] (bf16) and cmT[h][row] = c*m*Linv (f32).
__global__ __launch_bounds__(256, 2) void conv_mfma_fused(
        const __hip_bfloat16* __restrict__ xbf,
        const __hip_bfloat16* __restrict__ WcombT,
        const float* __restrict__ cb1, const float* __restrict__ cb3,
        const float* __restrict__ cb5,
        const int* __restrict__ masks, const float* __restrict__ Linv_buf,
        __hip_bfloat16* __restrict__ cbf, float* __restrict__ cmT) {
    __shared__ short8 sA[2][1024];   // [64 rows][16 chunks], 16KB per buf
    __shared__ short8 sB[2][768];    // [48 rows][16 chunks], 12KB per buf

    int blk = blockIdx.x;            // mt*16 + hc
    int mt = blk >> 4, hc = blk & 15;
    int tid = threadIdx.x, w = tid >> 6, lane = tid & 63;
    int fr = lane & 15, fq = lane >> 4;
    int row0 = mt * 64;
    int b = row0 >> 8, s0 = row0 & 255;
    const __hip_bfloat16* xbase = xbf + (b * SPAD + s0) * EMBED;
    const __hip_bfloat16* wbase = WcombT + (hc * 48) * 1280;

    short8 va[4], vb[3];
    auto LOADG = [&](int q) {
        int tap = q >> 1, e0 = (q & 1) * 128;
        const __hip_bfloat16* xs = xbase + tap * EMBED + e0;
        #pragma unroll
        for (int it = 0; it < 4; ++it) {
            int s = tid + it * 256, r = s >> 4, cg = s & 15;
            va[it] = *(const short8*)(xs + r * EMBED + cg * 8);
        }
        const __hip_bfloat16* wsrc = wbase + q * 128;
        #pragma unroll
        for (int it = 0; it < 3; ++it) {
            int s = tid + it * 256, r = s >> 4, cg = s & 15;
            vb[it] = *(const short8*)(wsrc + r * 1280 + cg * 8);
        }
    };
    auto WRITE = [&](int buf) {
        #pragma unroll
        for (int it = 0; it < 4; ++it) {
            int s = tid + it * 256, r = s >> 4, cg = s & 15;
            sA[buf][r * 16 + (cg ^ (r & 15))] = va[it];
        }
        #pragma unroll
        for (int it = 0; it < 3; ++it) {
            int s = tid + it * 256, r = s >> 4, cg = s & 15;
            sB[buf][r * 16 + (cg ^ (r & 15))] = vb[it];
        }
    };

    LOADG(0);
    WRITE(0);
    __syncthreads();

    f32x4 acc0 = {}, acc1 = {}, acc2 = {};
    int ra = w * 16 + fr;            // wave w owns rows w*16..+15
    int cur = 0;
    for (int q = 0; q < 10; ++q) {
        if (q < 9) LOADG(q + 1);
        #pragma unroll
        for (int ks = 0; ks < 4; ++ks) {
            int c = ks * 4 + fq;
            short8 a  = sA[cur][ra * 16 + (c ^ (ra & 15))];
            short8 q0 = sB[cur][fr * 16        + (c ^ fr)];
            short8 q1 = sB[cur][(16 + fr) * 16 + (c ^ fr)];
            short8 q2 = sB[cur][(32 + fr) * 16 + (c ^ fr)];
            acc0 = MFMA16(a, q0, acc0);
            acc1 = MFMA16(a, q1, acc1);
            acc2 = MFMA16(a, q2, acc2);
        }
        if (q < 9) WRITE(cur ^ 1);
        __syncthreads();
        cur ^= 1;
    }

    int h = hc * 16 + fr;
    float bb5 = cb5[h], bb3 = cb3[h], bb1 = cb1[h];
    float Linv = Linv_buf[b];
    #pragma unroll
    for (int j = 0; j < 4; ++j) {
        int row = row0 + w * 16 + fq * 4 + j;
        float t5 = fast_tanh(acc0[j] + bb5);
        float t3 = fast_tanh(acc1[j] + bb3);
        float t1 = fast_tanh(acc2[j] + bb1);
        float v = fmaxf(t1, fmaxf(t3, t5));
        cbf[row * HH + h] = __float2bfloat16(v);
        cmT[h * NROWS + row] = v * (float)masks[row] * Linv;
    }
}

// ---- g0/g1 GEMM; writes E = exp2(-log2e*(v+bias)) TRANSPOSED [h][row] ------
__global__ __launch_bounds__(256, 2) void gemm_g_mfma_kernel(
        const __hip_bfloat16* __restrict__ cbf,
        const __hip_bfloat16* __restrict__ W01T,
        const float* __restrict__ b0, const float* __restrict__ b1v,
        float* __restrict__ E0T, float* __restrict__ E1T) {
    int blk = blockIdx.x;            // 64 m-tiles * 8 n-tiles = 512
    int by = blk >> 3, bx = blk & 7;
    int tid = threadIdx.x;
    int w = tid >> 6, lane = tid & 63;
    int wr = w >> 1, wc = w & 1;
    int m0 = by * 32 + wr * 16;
    int n0 = bx * 64 + wc * 32;
    int fr = lane & 15, fq = lane >> 4;

    const short8* ap = (const short8*)(cbf + (m0 + fr) * HH + fq * 8);
    const short8* bptr0 = (const short8*)(W01T + (n0 + fr) * HH + fq * 8);
    const short8* bptr1 = (const short8*)(W01T + (n0 + 16 + fr) * HH + fq * 8);

    f32x4 acc[2] = {};
    #pragma unroll
    for (int ks = 0; ks < 8; ++ks) {
        short8 a = ap[ks * 4];
        acc[0] = MFMA16(a, bptr0[ks * 4], acc[0]);
        acc[1] = MFMA16(a, bptr1[ks * 4], acc[1]);
    }
    #pragma unroll
    for (int n = 0; n < 2; ++n) {
        int col = n0 + n * 16 + fr;
        float bias = (col < 256) ? b0[col] : b1v[col - 256];
        float* dst = (col < 256) ? (E0T + col * NROWS)
                                 : (E1T + (col - 256) * NROWS);
        #pragma unroll
        for (int j = 0; j < 4; ++j) {
            int row = m0 + fq * 4 + j;
            dst[row] = fast_exp2(NLOG2E * (acc[n][j] + bias));
        }
    }
}

// ---- relation: block=(b,h); threads=i; LDS j-loop; 100% occupancy ----------
__global__ __launch_bounds__(256) void relation_kernel(
        const float* __restrict__ E0T, const float* __restrict__ E1T,
        const float* __restrict__ cmT, const int* __restrict__ masks,
        float* __restrict__ relT) {
    int blk = blockIdx.x;            // b*256 + h
    int b = blk >> 8, h = blk & 255;
    int i = threadIdx.x;
    int row = b * SS + i;

    __shared__ f32x2 ps[SS];         // {e1, cm} per j
    {
        f32x2 pv;
        pv[0] = E1T[h * NROWS + row];    // coalesced
        pv[1] = cmT[h * NROWS + row];    // coalesced
        ps[i] = pv;
    }
    __syncthreads();

    float e0 = E0T[h * NROWS + row];     // coalesced
    float acc = 0.f;
    #pragma unroll 8
    for (int j = 0; j < SS; ++j) {
        f32x2 v = ps[j];                 // uniform -> LDS broadcast
        acc = fmaf(fast_rcp(fmaf(e0, v[0], 1.0f)), v[1], acc);
    }
    float mi = (float)masks[row];
    relT[h * NROWS + row] = fast_tanh(acc * mi);   // coalesced
}

// ---- final: coalesced relT reads, Wo in LDS, partial-reduce, softmax -------
// block = (b, 32 i's); threads = 8 h-groups x 32 i.
__global__ __launch_bounds__(256) void final_kernel(
        const float* __restrict__ relT,
        const float* __restrict__ Wo, const float* __restrict__ bo,
        float* __restrict__ out) {
    int blk = blockIdx.x;            // b*8 + iblk
    int b = blk >> 3, iblk = blk & 7;
    int tid = threadIdx.x;
    int hg = tid >> 5, il = tid & 31;
    int row = b * SS + iblk * 32 + il;

    __shared__ float wo_s[HH * NTAGS];       // 17.0 KB
    __shared__ float part[8][32][NTAGS];     // 17.4 KB

    for (int idx = tid; idx < HH * NTAGS; idx += 256) wo_s[idx] = Wo[idx];
    __syncthreads();

    float acc[NTAGS];
    #pragma unroll
    for (int t = 0; t < NTAGS; ++t) acc[t] = 0.f;
    const float* rbase = relT + row;
    for (int k = 0; k < 32; ++k) {
        int hh = hg * 32 + k;
        float v = rbase[hh * NROWS];         // 128B coalesced per 32 lanes
        const float* wrow = wo_s + hh * NTAGS;
        #pragma unroll
        for (int t = 0; t < NTAGS; ++t) acc[t] = fmaf(v, wrow[t], acc[t]);
    }
    #pragma unroll
    for (int t = 0; t < NTAGS; ++t) part[hg][il][t] = acc[t];
    __syncthreads();

    for (int idx = tid; idx < 32 * NTAGS; idx += 256) {
        int ii = idx / NTAGS, t = idx - ii * NTAGS;
        float s = bo[t];
        #pragma unroll
        for (int g = 0; g < 8; ++g) s += part[g][ii][t];
        part[0][ii][t] = s;
    }
    __syncthreads();

    if (tid < 32) {
        float mx = -1e30f;
        #pragma unroll
        for (int t = 0; t < NTAGS; ++t) mx = fmaxf(mx, part[0][tid][t]);
        float ex[NTAGS], sum = 0.f;
        #pragma unroll
        for (int t = 0; t < NTAGS; ++t) { ex[t] = __expf(part[0][tid][t] - mx); sum += ex[t]; }
        float si = fast_rcp(sum);
        int orow = b * SS + iblk * 32 + tid;
        #pragma unroll
        for (int t = 0; t < NTAGS; ++t)
            out[orow * NTAGS + t] = ex[t] * si;
    }
}

extern "C" void kernel_launch(void* const* d_in, const int* in_sizes, int n_in,
                              void* d_out, int out_size, void* d_ws, size_t ws_size,
                              hipStream_t stream) {
    const int*   tokens     = (const int*)d_in[0];
    const int*   masks      = (const int*)d_in[1];
    const float* char_emb   = (const float*)d_in[2];
    const float* bigram_emb = (const float*)d_in[3];
    const float* conv1_w    = (const float*)d_in[4];
    const float* conv1_b    = (const float*)d_in[5];
    const float* conv3_w    = (const float*)d_in[6];
    const float* conv3_b    = (const float*)d_in[7];
    const float* conv5_w    = (const float*)d_in[8];
    const float* conv5_b    = (const float*)d_in[9];
    const float* W0         = (const float*)d_in[10];
    const float* b0         = (const float*)d_in[11];
    const float* W1         = (const float*)d_in[12];
    const float* b1         = (const float*)d_in[13];
    const float* Wo         = (const float*)d_in[14];
    const float* bo         = (const float*)d_in[15];
    float* out = (float*)d_out;

    char* p = (char*)d_ws;
    __hip_bfloat16* xbf    = (__hip_bfloat16*)p;  p += BB * SPAD * EMBED * 2;   // 1.06 MB
    __hip_bfloat16* WcombT = (__hip_bfloat16*)p;  p += 768 * 1280 * 2;          // 1.97 MB
    __hip_bfloat16* W01T   = (__hip_bfloat16*)p;  p += 512 * 256 * 2;           // 0.26 MB
    __hip_bfloat16* cbf    = (__hip_bfloat16*)p;  p += NROWS * HH * 2;          // 1.05 MB
    float* cmT  = (float*)p;  p += (size_t)HH * NROWS * 4;                      // 2.1 MB
    float* E0T  = (float*)p;  p += (size_t)HH * NROWS * 4;                      // 2.1 MB
    float* E1T  = (float*)p;  p += (size_t)HH * NROWS * 4;                      // 2.1 MB
    float* relT = (float*)p;  p += (size_t)HH * NROWS * 4;                      // 2.1 MB
    float* Linv_buf = (float*)p;  p += 64;

    embed_pack_kernel<<<BB * SPAD + 160 + 256 + 1, 256, 0, stream>>>(
        tokens, char_emb, bigram_emb, conv1_w, conv3_w, conv5_w, W0, W1,
        masks, xbf, WcombT, W01T, Linv_buf);
    conv_mfma_fused<<<512, 256, 0, stream>>>(xbf, WcombT, conv1_b, conv3_b,
                                             conv5_b, masks, Linv_buf, cbf, cmT);
    gemm_g_mfma_kernel<<<512, 256, 0, stream>>>(cbf, W01T, b0, b1, E0T, E1T);
    relation_kernel<<<BB * 256, 256, 0, stream>>>(E0T, E1T, cmT, masks, relT);
    final_kernel<<<BB * 8, 256, 0, stream>>>(relT, Wo, bo, out);
}

// Round 15
// 58.950 us; speedup vs baseline: 1.6345x; 1.0004x over previous
//
#include <hip/hip_runtime.h>
#include <hip/hip_bf16.h>

#define BB 8
#define SS 256
#define CHAR_E 128
#define BI_E 64
#define EMBED 256
#define HH 256
#define NTAGS 17
#define SPAD 260   // S + 2 zero-pad rows each side
#define NROWS 2048 // B*S
#define NLOG2E -1.4426950408889634f

typedef __attribute__((ext_vector_type(8))) short short8;
typedef __attribute__((ext_vector_type(4))) float f32x4;
typedef __attribute__((ext_vector_type(2))) float f32x2;
#define MFMA16(a, b, c) __builtin_amdgcn_mfma_f32_16x16x32_bf16(a, b, c, 0, 0, 0)

__device__ __forceinline__ float fast_rcp(float x) {
    return __builtin_amdgcn_rcpf(x);
}
__device__ __forceinline__ float fast_exp2(float x) {
    return __builtin_amdgcn_exp2f(x);
}
__device__ __forceinline__ float fast_tanh(float x) {
    float e = __expf(2.0f * x);
    return 1.0f - 2.0f * fast_rcp(e + 1.0f);
}

// ---- fused: embed gather -> xbf; pack WcombT/W01T; lengths -----------------
__global__ __launch_bounds__(256) void embed_pack_kernel(
        const int* __restrict__ tokens,
        const float* __restrict__ char_emb,
        const float* __restrict__ bigram_emb,
        const float* __restrict__ w1, const float* __restrict__ w3,
        const float* __restrict__ w5,
        const float* __restrict__ W0, const float* __restrict__ W1mat,
        const int* __restrict__ masks,
        __hip_bfloat16* __restrict__ xbf,
        __hip_bfloat16* __restrict__ WcombT,
        __hip_bfloat16* __restrict__ W01T,
        float* __restrict__ Linv_buf) {
    int blk = blockIdx.x;
    int t = threadIdx.x;
    if (blk < BB * SPAD) {
        int b = blk / SPAD, r = blk % SPAD;
        float v = 0.0f;
        if (r >= 2 && r < SS + 2) {
            int s = r - 2;
            const int* tk = tokens + (b * SS + s) * 3;
            if (t < CHAR_E)              v = char_emb[tk[0] * CHAR_E + t];
            else if (t < CHAR_E + BI_E)  v = bigram_emb[tk[1] * BI_E + (t - CHAR_E)];
            else                         v = bigram_emb[tk[2] * BI_E + (t - CHAR_E - BI_E)];
        }
        xbf[blk * EMBED + t] = __float2bfloat16(v);
    } else if (blk < BB * SPAD + 160) {
        // WcombT pack: block = 8 kk-cols, thread = h; short8 (16B) stores
        int kk0 = (blk - BB * SPAD) * 8;
        int h = t, hc = h >> 4, hl = h & 15;
        union { short8 v; __hip_bfloat16 b[8]; } u5, u3, u1;
        #pragma unroll
        for (int k = 0; k < 8; ++k) {
            int kk = kk0 + k, tap = kk >> 8, e = kk & 255;
            float f5 = w5[(tap * EMBED + e) * HH + h];
            float f3 = (tap >= 1 && tap <= 3) ? w3[((tap - 1) * EMBED + e) * HH + h] : 0.f;
            float f1 = (tap == 2) ? w1[e * HH + h] : 0.f;
            u5.b[k] = __float2bfloat16(f5);
            u3.b[k] = __float2bfloat16(f3);
            u1.b[k] = __float2bfloat16(f1);
        }
        *(short8*)(WcombT + (hc * 48 +  0 + hl) * 1280 + kk0) = u5.v;
        *(short8*)(WcombT + (hc * 48 + 16 + hl) * 1280 + kk0) = u3.v;
        *(short8*)(WcombT + (hc * 48 + 32 + hl) * 1280 + kk0) = u1.v;
    } else if (blk < BB * SPAD + 160 + 256) {
        // W01T pack: block = e, threads = h (reads coalesced over h)
        int e = blk - BB * SPAD - 160;
        W01T[t * 256 + e]         = __float2bfloat16(W0[e * HH + t]);
        W01T[(256 + t) * 256 + e] = __float2bfloat16(W1mat[e * HH + t]);
    } else {
        // lengths: b = t>>5, 32 lanes each sum 8 masks, shuffle-reduce
        int b = t >> 5, l = t & 31;
        int ssum = 0;
        #pragma unroll
        for (int k = 0; k < 8; ++k) ssum += masks[b * SS + l * 8 + k];
        #pragma unroll
        for (int o = 16; o; o >>= 1) ssum += __shfl_xor(ssum, o);
        if (l == 0) Linv_buf[b] = (ssum > 0) ? (1.0f / (float)ssum) : 0.0f;
    }
}

// ---- conv as LDS-tiled MFMA GEMM (BM=64, BN=48, BK=128, dbuf) --------------
// Epilogue: tanh+max -> cbf[row][h] (bf16) and cmT[h][row] = c*m*Linv (f32).
__global__ __launch_bounds__(256, 2) void conv_mfma_fused(
        const __hip_bfloat16* __restrict__ xbf,
        const __hip_bfloat16* __restrict__ WcombT,
        const float* __restrict__ cb1, const float* __restrict__ cb3,
        const float* __restrict__ cb5,
        const int* __restrict__ masks, const float* __restrict__ Linv_buf,
        __hip_bfloat16* __restrict__ cbf, float* __restrict__ cmT) {
    __shared__ short8 sA[2][1024];   // [64 rows][16 chunks], 16KB per buf
    __shared__ short8 sB[2][768];    // [48 rows][16 chunks], 12KB per buf

    int blk = blockIdx.x;            // mt*16 + hc
    int mt = blk >> 4, hc = blk & 15;
    int tid = threadIdx.x, w = tid >> 6, lane = tid & 63;
    int fr = lane & 15, fq = lane >> 4;
    int row0 = mt * 64;
    int b = row0 >> 8, s0 = row0 & 255;
    const __hip_bfloat16* xbase = xbf + (b * SPAD + s0) * EMBED;
    const __hip_bfloat16* wbase = WcombT + (hc * 48) * 1280;

    short8 va[4], vb[3];
    auto LOADG = [&](int q) {
        int tap = q >> 1, e0 = (q & 1) * 128;
        const __hip_bfloat16* xs = xbase + tap * EMBED + e0;
        #pragma unroll
        for (int it = 0; it < 4; ++it) {
            int s = tid + it * 256, r = s >> 4, cg = s & 15;
            va[it] = *(const short8*)(xs + r * EMBED + cg * 8);
        }
        const __hip_bfloat16* wsrc = wbase + q * 128;
        #pragma unroll
        for (int it = 0; it < 3; ++it) {
            int s = tid + it * 256, r = s >> 4, cg = s & 15;
            vb[it] = *(const short8*)(wsrc + r * 1280 + cg * 8);
        }
    };
    auto WRITE = [&](int buf) {
        #pragma unroll
        for (int it = 0; it < 4; ++it) {
            int s = tid + it * 256, r = s >> 4, cg = s & 15;
            sA[buf][r * 16 + (cg ^ (r & 15))] = va[it];
        }
        #pragma unroll
        for (int it = 0; it < 3; ++it) {
            int s = tid + it * 256, r = s >> 4, cg = s & 15;
            sB[buf][r * 16 + (cg ^ (r & 15))] = vb[it];
        }
    };

    LOADG(0);
    WRITE(0);
    __syncthreads();

    f32x4 acc0 = {}, acc1 = {}, acc2 = {};
    int ra = w * 16 + fr;            // wave w owns rows w*16..+15
    int cur = 0;
    for (int q = 0; q < 10; ++q) {
        if (q < 9) LOADG(q + 1);
        #pragma unroll
        for (int ks = 0; ks < 4; ++ks) {
            int c = ks * 4 + fq;
            short8 a  = sA[cur][ra * 16 + (c ^ (ra & 15))];
            short8 q0 = sB[cur][fr * 16        + (c ^ fr)];
            short8 q1 = sB[cur][(16 + fr) * 16 + (c ^ fr)];
            short8 q2 = sB[cur][(32 + fr) * 16 + (c ^ fr)];
            acc0 = MFMA16(a, q0, acc0);
            acc1 = MFMA16(a, q1, acc1);
            acc2 = MFMA16(a, q2, acc2);
        }
        if (q < 9) WRITE(cur ^ 1);
        __syncthreads();
        cur ^= 1;
    }

    int h = hc * 16 + fr;
    float bb5 = cb5[h], bb3 = cb3[h], bb1 = cb1[h];
    float Linv = Linv_buf[b];
    #pragma unroll
    for (int j = 0; j < 4; ++j) {
        int row = row0 + w * 16 + fq * 4 + j;
        float t5 = fast_tanh(acc0[j] + bb5);
        float t3 = fast_tanh(acc1[j] + bb3);
        float t1 = fast_tanh(acc2[j] + bb1);
        float v = fmaxf(t1, fmaxf(t3, t5));
        cbf[row * HH + h] = __float2bfloat16(v);
        cmT[h * NROWS + row] = v * (float)masks[row] * Linv;
    }
}

// ---- g0/g1 GEMM; full register prefetch; E=exp2(-log2e*(v+bias)) -----------
// Outputs TRANSPOSED [h][row] via LDS transpose (coalesced 32B stores).
__global__ __launch_bounds__(256) void gemm_g_mfma_kernel(
        const __hip_bfloat16* __restrict__ cbf,
        const __hip_bfloat16* __restrict__ W01T,
        const float* __restrict__ b0, const float* __restrict__ b1v,
        float* __restrict__ E0T, float* __restrict__ E1T) {
    __shared__ float s_out[64][33];  // [colLocal][rowLocal], padded

    int blk = blockIdx.x;            // 64 m-tiles * 8 n-tiles = 512
    int by = blk >> 3, bx = blk & 7;
    int tid = threadIdx.x;
    int w = tid >> 6, lane = tid & 63;
    int wr = w >> 1, wc = w & 1;
    int m0 = by * 32 + wr * 16;
    int n0 = bx * 64 + wc * 32;
    int fr = lane & 15, fq = lane >> 4;

    const short8* ap  = (const short8*)(cbf + (m0 + fr) * HH + fq * 8);
    const short8* bp0 = (const short8*)(W01T + (n0 + fr) * HH + fq * 8);
    const short8* bp1 = (const short8*)(W01T + (n0 + 16 + fr) * HH + fq * 8);

    short8 af[8], bf0[8], bf1[8];    // all 24 loads issued up front
    #pragma unroll
    for (int ks = 0; ks < 8; ++ks) af[ks] = ap[ks * 4];
    #pragma unroll
    for (int ks = 0; ks < 8; ++ks) { bf0[ks] = bp0[ks * 4]; bf1[ks] = bp1[ks * 4]; }

    f32x4 acc[2] = {};
    #pragma unroll
    for (int ks = 0; ks < 8; ++ks) {
        acc[0] = MFMA16(af[ks], bf0[ks], acc[0]);
        acc[1] = MFMA16(af[ks], bf1[ks], acc[1]);
    }
    #pragma unroll
    for (int n = 0; n < 2; ++n) {
        int col = n0 + n * 16 + fr;
        float bias = (col < 256) ? b0[col] : b1v[col - 256];
        int cl = wc * 32 + n * 16 + fr;
        #pragma unroll
        for (int j = 0; j < 4; ++j) {
            int rl = wr * 16 + fq * 4 + j;
            s_out[cl][rl] = fast_exp2(NLOG2E * (acc[n][j] + bias));
        }
    }
    __syncthreads();
    {
        float* dstbase = (bx < 4) ? (E0T + (bx * 64) * NROWS)
                                  : (E1T + (bx * 64 - 256) * NROWS);
        int cl = tid >> 2, rq = tid & 3;   // 64 cols x 4 row-octets
        f32x4 o0, o1;
        #pragma unroll
        for (int k = 0; k < 4; ++k) { o0[k] = s_out[cl][rq * 8 + k];
                                      o1[k] = s_out[cl][rq * 8 + 4 + k]; }
        float* dst = dstbase + cl * NROWS + by * 32 + rq * 8;
        *(f32x4*)dst = o0;
        *(f32x4*)(dst + 4) = o1;
    }
}

// ---- relation: block=(b,h); threads=i; LDS j-loop; 100% occupancy ----------
__global__ __launch_bounds__(256) void relation_kernel(
        const float* __restrict__ E0T, const float* __restrict__ E1T,
        const float* __restrict__ cmT, const int* __restrict__ masks,
        float* __restrict__ relT) {
    int blk = blockIdx.x;            // b*256 + h
    int b = blk >> 8, h = blk & 255;
    int i = threadIdx.x;
    int row = b * SS + i;

    __shared__ f32x2 ps[SS];         // {e1, cm} per j
    {
        f32x2 pv;
        pv[0] = E1T[h * NROWS + row];    // coalesced
        pv[1] = cmT[h * NROWS + row];    // coalesced
        ps[i] = pv;
    }
    __syncthreads();

    float e0 = E0T[h * NROWS + row];     // coalesced
    float acc = 0.f;
    #pragma unroll 8
    for (int j = 0; j < SS; ++j) {
        f32x2 v = ps[j];                 // uniform -> LDS broadcast
        acc = fmaf(fast_rcp(fmaf(e0, v[0], 1.0f)), v[1], acc);
    }
    float mi = (float)masks[row];
    relT[h * NROWS + row] = fast_tanh(acc * mi);   // coalesced
}

// ---- final: coalesced relT reads, Wo in LDS, partial-reduce, softmax -------
// block = (b, 32 i's); threads = 8 h-groups x 32 i.
__global__ __launch_bounds__(256) void final_kernel(
        const float* __restrict__ relT,
        const float* __restrict__ Wo, const float* __restrict__ bo,
        float* __restrict__ out) {
    int blk = blockIdx.x;            // b*8 + iblk
    int b = blk >> 3, iblk = blk & 7;
    int tid = threadIdx.x;
    int hg = tid >> 5, il = tid & 31;
    int row = b * SS + iblk * 32 + il;

    __shared__ float wo_s[HH * NTAGS];       // 17.0 KB
    __shared__ float part[8][32][NTAGS];     // 17.4 KB

    for (int idx = tid; idx < HH * NTAGS; idx += 256) wo_s[idx] = Wo[idx];
    __syncthreads();

    float acc[NTAGS];
    #pragma unroll
    for (int t = 0; t < NTAGS; ++t) acc[t] = 0.f;
    const float* rbase = relT + row;
    for (int k = 0; k < 32; ++k) {
        int hh = hg * 32 + k;
        float v = rbase[hh * NROWS];         // 128B coalesced per 32 lanes
        const float* wrow = wo_s + hh * NTAGS;
        #pragma unroll
        for (int t = 0; t < NTAGS; ++t) acc[t] = fmaf(v, wrow[t], acc[t]);
    }
    #pragma unroll
    for (int t = 0; t < NTAGS; ++t) part[hg][il][t] = acc[t];
    __syncthreads();

    for (int idx = tid; idx < 32 * NTAGS; idx += 256) {
        int ii = idx / NTAGS, t = idx - ii * NTAGS;
        float s = bo[t];
        #pragma unroll
        for (int g = 0; g < 8; ++g) s += part[g][ii][t];
        part[0][ii][t] = s;
    }
    __syncthreads();

    if (tid < 32) {
        float mx = -1e30f;
        #pragma unroll
        for (int t = 0; t < NTAGS; ++t) mx = fmaxf(mx, part[0][tid][t]);
        float ex[NTAGS], sum = 0.f;
        #pragma unroll
        for (int t = 0; t < NTAGS; ++t) { ex[t] = __expf(part[0][tid][t] - mx); sum += ex[t]; }
        float si = fast_rcp(sum);
        int orow = b * SS + iblk * 32 + tid;
        #pragma unroll
        for (int t = 0; t < NTAGS; ++t)
            out[orow * NTAGS + t] = ex[t] * si;
    }
}

extern "C" void kernel_launch(void* const* d_in, const int* in_sizes, int n_in,
                              void* d_out, int out_size, void* d_ws, size_t ws_size,
                              hipStream_t stream) {
    const int*   tokens     = (const int*)d_in[0];
    const int*   masks      = (const int*)d_in[1];
    const float* char_emb   = (const float*)d_in[2];
    const float* bigram_emb = (const float*)d_in[3];
    const float* conv1_w    = (const float*)d_in[4];
    const float* conv1_b    = (const float*)d_in[5];
    const float* conv3_w    = (const float*)d_in[6];
    const float* conv3_b    = (const float*)d_in[7];
    const float* conv5_w    = (const float*)d_in[8];
    const float* conv5_b    = (const float*)d_in[9];
    const float* W0         = (const float*)d_in[10];
    const float* b0         = (const float*)d_in[11];
    const float* W1         = (const float*)d_in[12];
    const float* b1         = (const float*)d_in[13];
    const float* Wo         = (const float*)d_in[14];
    const float* bo         = (const float*)d_in[15];
    float* out = (float*)d_out;

    char* p = (char*)d_ws;
    __hip_bfloat16* xbf    = (__hip_bfloat16*)p;  p += BB * SPAD * EMBED * 2;   // 1.06 MB
    __hip_bfloat16* WcombT = (__hip_bfloat16*)p;  p += 768 * 1280 * 2;          // 1.97 MB
    __hip_bfloat16* W01T   = (__hip_bfloat16*)p;  p += 512 * 256 * 2;           // 0.26 MB
    __hip_bfloat16* cbf    = (__hip_bfloat16*)p;  p += NROWS * HH * 2;          // 1.05 MB
    float* cmT  = (float*)p;  p += (size_t)HH * NROWS * 4;                      // 2.1 MB
    float* E0T  = (float*)p;  p += (size_t)HH * NROWS * 4;                      // 2.1 MB
    float* E1T  = (float*)p;  p += (size_t)HH * NROWS * 4;                      // 2.1 MB
    float* relT = (float*)p;  p += (size_t)HH * NROWS * 4;                      // 2.1 MB
    float* Linv_buf = (float*)p;  p += 64;

    embed_pack_kernel<<<BB * SPAD + 160 + 256 + 1, 256, 0, stream>>>(
        tokens, char_emb, bigram_emb, conv1_w, conv3_w, conv5_w, W0, W1,
        masks, xbf, WcombT, W01T, Linv_buf);
    conv_mfma_fused<<<512, 256, 0, stream>>>(xbf, WcombT, conv1_b, conv3_b,
                                             conv5_b, masks, Linv_buf, cbf, cmT);
    gemm_g_mfma_kernel<<<512, 256, 0, stream>>>(cbf, W01T, b0, b1, E0T, E1T);
    relation_kernel<<<BB * 256, 256, 0, stream>>>(E0T, E1T, cmT, masks, relT);
    final_kernel<<<BB * 8, 256, 0, stream>>>(relT, Wo, bo, out);
}